// Round 10
// baseline (303.500 us; speedup 1.0000x reference)
//
#include <hip/hip_runtime.h>
#include <math.h>

#define NCLASS 40
#define BEDG4 4096  // edges per chunk block in CSR build
#define CAP 24576   // LDS col-staging capacity per 512-node sub-bucket

typedef float f32x4 __attribute__((ext_vector_type(4)));
typedef float f32x2 __attribute__((ext_vector_type(2)));
typedef __bf16 bf16x8 __attribute__((ext_vector_type(8)));

typedef __attribute__((address_space(1))) const void gv_t;
typedef __attribute__((address_space(3))) void lv_t;
#define GLOAD_LDS16(g, l) __builtin_amdgcn_global_load_lds((gv_t*)(g), (lv_t*)(l), 16, 0, 0)
#define NTL(p) __builtin_nontemporal_load(p)

__device__ inline unsigned short f2bf(float f) {
  unsigned u = __float_as_uint(f);
  unsigned r = (u + 0x7fff + ((u >> 16) & 1)) >> 16;
  return (unsigned short)r;
}
__device__ inline float bflo(unsigned v) { return __uint_as_float(v << 16); }
__device__ inline float bfhi(unsigned v) { return __uint_as_float(v & 0xffff0000u); }

// decode 8 fp8 (one uint2) and accumulate with scale
#define ACCQ2(u, sc)                                                  \
  do {                                                                \
    f32x2 p_;                                                         \
    p_ = __builtin_amdgcn_cvt_pk_f32_fp8(u.x, false);                 \
    acc[0] = fmaf(p_.x, sc, acc[0]); acc[1] = fmaf(p_.y, sc, acc[1]); \
    p_ = __builtin_amdgcn_cvt_pk_f32_fp8(u.x, true);                  \
    acc[2] = fmaf(p_.x, sc, acc[2]); acc[3] = fmaf(p_.y, sc, acc[3]); \
    p_ = __builtin_amdgcn_cvt_pk_f32_fp8(u.y, false);                 \
    acc[4] = fmaf(p_.x, sc, acc[4]); acc[5] = fmaf(p_.y, sc, acc[5]); \
    p_ = __builtin_amdgcn_cvt_pk_f32_fp8(u.y, true);                  \
    acc[6] = fmaf(p_.x, sc, acc[6]); acc[7] = fmaf(p_.y, sc, acc[7]); \
  } while (0)

// decode 4 bf16 (one uint2) and accumulate with scale
#define ACC4(u, sc)                     \
  acc[0] = fmaf(bflo(u.x), sc, acc[0]); \
  acc[1] = fmaf(bfhi(u.x), sc, acc[1]); \
  acc[2] = fmaf(bflo(u.y), sc, acc[2]); \
  acc[3] = fmaf(bfhi(u.y), sc, acc[3]);

// ============ CSR build: single-level counting sort by 512-node range =========
__global__ __launch_bounds__(256) void k_bcountF(const int* __restrict__ dst, int E,
                                                 int* __restrict__ bcnt) {
  __shared__ int lc[256];
  int k = blockIdx.x;
  int tid = threadIdx.x;
  lc[tid] = 0;
  __syncthreads();
  int lo = k * BEDG4, hi = min(lo + BEDG4, E);
  for (int i = lo + tid; i < hi; i += 256) atomicAdd(&lc[NTL(&dst[i]) >> 9], 1);
  __syncthreads();
  bcnt[k * 256 + tid] = lc[tid];
}

__global__ __launch_bounds__(256) void k_bscanF(int* __restrict__ bcnt, int nbB,
                                                int* __restrict__ tot) {
  __shared__ int tmp[256];
  __shared__ int carryS;
  int b = blockIdx.x;
  int tid = threadIdx.x;
  if (tid == 0) carryS = 0;
  __syncthreads();
  for (int c0 = 0; c0 < nbB; c0 += 256) {
    int idx = c0 + tid;
    int v = (idx < nbB) ? bcnt[idx * 256 + b] : 0;
    tmp[tid] = v;
    __syncthreads();
    for (int d = 1; d < 256; d <<= 1) {
      int t = (tid >= d) ? tmp[tid - d] : 0;
      __syncthreads();
      tmp[tid] += t;
      __syncthreads();
    }
    if (idx < nbB) bcnt[idx * 256 + b] = carryS + tmp[tid] - v;
    __syncthreads();
    if (tid == 255) carryS += tmp[255];
    __syncthreads();
  }
  if (tid == 0) tot[b] = carryS;
}

__global__ __launch_bounds__(256) void k_baseF(const int* __restrict__ tot, int NSB,
                                               int N, int E, int* __restrict__ base2,
                                               int* __restrict__ off) {
  __shared__ int tmp[256];
  int tid = threadIdx.x;
  int v = (tid < NSB) ? tot[tid] : 0;
  tmp[tid] = v;
  __syncthreads();
  for (int d = 1; d < 256; d <<= 1) {
    int t = (tid >= d) ? tmp[tid - d] : 0;
    __syncthreads();
    tmp[tid] += t;
    __syncthreads();
  }
  base2[tid] = tmp[tid] - v;
  if (tid == 0) {
    base2[NSB] = E;
    off[N] = E;
  }
}

__global__ __launch_bounds__(256) void k_placeF(const int* __restrict__ dst,
                                                const int* __restrict__ src, int E,
                                                const int* __restrict__ bcnt,
                                                const int* __restrict__ base2,
                                                int* __restrict__ ebuf2) {
  __shared__ int lb[256];
  int k = blockIdx.x;
  int tid = threadIdx.x;
  lb[tid] = base2[tid] + bcnt[k * 256 + tid];
  __syncthreads();
  int lo = k * BEDG4, hi = min(lo + BEDG4, E);
  for (int i = lo + tid; i < hi; i += 256) {
    int d = NTL(&dst[i]);
    int s = NTL(&src[i]);
    int pos = atomicAdd(&lb[d >> 9], 1);
    ebuf2[pos] = (int)(((unsigned)(d & 511) << 17) | (unsigned)s);
  }
}

__global__ __launch_bounds__(256) void k_csrF(const int* __restrict__ ebuf2,
                                              const int* __restrict__ base2,
                                              const int* __restrict__ tot, int N,
                                              int* __restrict__ off,
                                              int* __restrict__ col) {
  __shared__ int cnt[512];
  __shared__ int cur[512];
  __shared__ int tmp[256];
  __shared__ int stage[CAP];
  int sb = blockIdx.x;
  int tid = threadIdx.x;
  int node0 = sb << 9;
  if (node0 >= N) return;
  int nn = min(512, N - node0);
  int lo = base2[sb];
  int t2 = tot[sb];

  cnt[tid] = 0;
  cnt[tid + 256] = 0;
  __syncthreads();
  for (int i = lo + tid; i < lo + t2; i += 256)
    atomicAdd(&cnt[(((unsigned)ebuf2[i]) >> 17) & 511], 1);
  __syncthreads();

  int v0 = cnt[2 * tid], v1 = cnt[2 * tid + 1];
  int s = v0 + v1;
  tmp[tid] = s;
  __syncthreads();
  for (int d = 1; d < 256; d <<= 1) {
    int t = (tid >= d) ? tmp[tid - d] : 0;
    __syncthreads();
    tmp[tid] += t;
    __syncthreads();
  }
  int excl = tmp[tid] - s;
  cnt[2 * tid] = excl;
  cnt[2 * tid + 1] = excl + v0;
  cur[2 * tid] = excl;
  cur[2 * tid + 1] = excl + v0;
  __syncthreads();

  for (int i = tid; i < nn; i += 256) off[node0 + i] = lo + cnt[i];

  if (t2 <= CAP) {
    for (int i = lo + tid; i < lo + t2; i += 256) {
      unsigned pk = (unsigned)ebuf2[i];
      int pos = atomicAdd(&cur[(pk >> 17) & 511], 1);
      stage[pos] = (int)(pk & 0x1FFFFu);
    }
    __syncthreads();
    for (int i = tid; i < t2; i += 256) col[lo + i] = stage[i];
  } else {
    for (int i = lo + tid; i < lo + t2; i += 256) {
      unsigned pk = (unsigned)ebuf2[i];
      int pos = atomicAdd(&cur[(pk >> 17) & 511], 1);
      col[lo + pos] = (int)(pk & 0x1FFFFu);
    }
  }
}

// ---------------- casts / weight prep ----------------
__global__ void k_cast(const float4* __restrict__ x, uint4* __restrict__ xb,
                       uint2* __restrict__ xq, int n8) {
  int i = blockIdx.x * blockDim.x + threadIdx.x;
  if (i >= n8) return;
  float4 a = x[i * 2], b = x[i * 2 + 1];
  uint4 o;
  o.x = (unsigned)f2bf(a.x) | ((unsigned)f2bf(a.y) << 16);
  o.y = (unsigned)f2bf(a.z) | ((unsigned)f2bf(a.w) << 16);
  o.z = (unsigned)f2bf(b.x) | ((unsigned)f2bf(b.y) << 16);
  o.w = (unsigned)f2bf(b.z) | ((unsigned)f2bf(b.w) << 16);
  xb[i] = o;
  unsigned lo = __builtin_amdgcn_cvt_pk_fp8_f32(a.x, a.y, 0, false);
  lo = __builtin_amdgcn_cvt_pk_fp8_f32(a.z, a.w, lo, true);
  unsigned hi = __builtin_amdgcn_cvt_pk_fp8_f32(b.x, b.y, 0, false);
  hi = __builtin_amdgcn_cvt_pk_fp8_f32(b.z, b.w, hi, true);
  xq[i] = make_uint2(lo, hi);
}

// Wth layout: [half][COLS][128] bf16. half0=Wl^T, half1=Wr^T.
__global__ void k_prepw(const float* __restrict__ W1l, const float* __restrict__ W1r,
                        const float* __restrict__ W2l, const float* __restrict__ W2r,
                        const float* __restrict__ W3l, const float* __restrict__ W3r,
                        unsigned short* __restrict__ Wth1, unsigned short* __restrict__ Wth2,
                        unsigned short* __restrict__ Wth3) {
  int idx = blockIdx.x * blockDim.x + threadIdx.x;
  if (idx < 32768) {
    int h = idx >> 14, c = (idx >> 7) & 127, k = idx & 127;
    const float* W = h ? W1r : W1l;
    Wth1[idx] = f2bf(W[k * 128 + c]);
  } else if (idx < 65536) {
    int j = idx - 32768;
    int h = j >> 14, c = (j >> 7) & 127, k = j & 127;
    const float* W = h ? W2r : W2l;
    Wth2[j] = f2bf(W[k * 128 + c]);
  } else if (idx < 65536 + 16384) {
    int j = idx - 65536;
    int h = j >> 13, c = (j >> 7) & 63, k = j & 127;
    float v = 0.f;
    if (c < NCLASS) v = (h ? W3r : W3l)[k * NCLASS + c];
    Wth3[j] = f2bf(v);
  }
}

// ------- mean aggregation, width 128, fp8 rows: 16 lanes/row, uint2/lane -------
// 4 edge-groups, 2 loads in flight (8 edges/iter); 8 acc; 2 shuffle rounds.
__global__ void k_aggq(const char* __restrict__ Xq, const int* __restrict__ off,
                       const int* __restrict__ col, int n, uint4* __restrict__ out) {
  int wid = (blockIdx.x * blockDim.x + threadIdx.x) >> 6;
  int lane = threadIdx.x & 63;
  if (wid >= n) return;
  int g = lane >> 4, q = lane & 15;
  unsigned qb = (unsigned)q << 3;  // 8 B per lane
  int s = off[wid], e = off[wid + 1];
  float acc[8];
#pragma unroll
  for (int t = 0; t < 8; ++t) acc[t] = 0.f;
  int e1 = e - 1;
  for (int j = s; j < e; j += 8) {
    int i0 = j + g, i1 = i0 + 4;
    int c0 = NTL(&col[min(i0, e1)]);
    int c1 = NTL(&col[min(i1, e1)]);
    float s0 = (i0 < e) ? 1.f : 0.f;
    float s1 = (i1 < e) ? 1.f : 0.f;
    uint2 u0 = *(const uint2*)(Xq + (((unsigned)c0 << 7) + qb));
    uint2 u1 = *(const uint2*)(Xq + (((unsigned)c1 << 7) + qb));
    ACCQ2(u0, s0);
    ACCQ2(u1, s1);
  }
#pragma unroll
  for (int t = 0; t < 8; ++t) {
    acc[t] += __shfl_xor(acc[t], 16);
    acc[t] += __shfl_xor(acc[t], 32);
  }
  float inv = 1.0f / fmaxf((float)(e - s), 1.0f);
  if (lane < 16) {
    uint4 o;
    o.x = (unsigned)f2bf(acc[0] * inv) | ((unsigned)f2bf(acc[1] * inv) << 16);
    o.y = (unsigned)f2bf(acc[2] * inv) | ((unsigned)f2bf(acc[3] * inv) << 16);
    o.z = (unsigned)f2bf(acc[4] * inv) | ((unsigned)f2bf(acc[5] * inv) << 16);
    o.w = (unsigned)f2bf(acc[6] * inv) | ((unsigned)f2bf(acc[7] * inv) << 16);
    out[(size_t)wid * 16 + q] = o;
  }
}

// ---------------- MFMA GEMM ----------------
// EPI 0: relu -> outB bf16 [n][128] AND (fp8*)outF [n][128]
// EPI 1: relu -> outB bf16 [n][128] AND outF f32 [n][128]
// EPI 3: cols 0..63 -> outB bf16 [n][64] (Y3); cols 64..127 -> (bf16*)outF [n][64] (R3)
template <int COLS, int HALVES, int EPI>
__global__ __launch_bounds__(256) void k_gemm_mfma(
    const unsigned short* __restrict__ Aagg, const unsigned short* __restrict__ Aroot,
    const unsigned short* __restrict__ Wth, const float* __restrict__ bias, int n,
    float* __restrict__ outF, unsigned short* __restrict__ outB) {
  constexpr int RF = 4;
  constexpr int CF = 4;
  __shared__ unsigned short aS[128 * 128];
  __shared__ unsigned short wS[COLS * 128];
  int tid = threadIdx.x;
  int w = tid >> 6, lane = tid & 63, l15 = lane & 15, kg = lane >> 4;
  int rowBase = blockIdx.x * 128;
  int r0 = (w >> 1) * 64;
  int c0 = (w & 1) * 64;

  f32x4 acc[RF][CF];
#pragma unroll
  for (int i = 0; i < RF; ++i)
#pragma unroll
    for (int j = 0; j < CF; ++j) acc[i][j] = (f32x4){0.f, 0.f, 0.f, 0.f};

#pragma unroll
  for (int half = 0; half < HALVES; ++half) {
    if (half) __syncthreads();
    {
      const unsigned short* As = half ? Aroot : Aagg;
#pragma unroll
      for (int it = 0; it < 8; ++it) {
        int row = it * 16 + (tid >> 4);
        int g = rowBase + row;
        g = (g < n) ? g : (n - 1);
        int cb = (tid & 15) << 4;
        int sb = cb ^ ((row & 7) << 4);
        const char* src = (const char*)(As + (size_t)g * 128) + sb;
        char* dst = (char*)aS + it * 4096 + (tid >> 6) * 1024;
        GLOAD_LDS16(src, dst);
      }
      const unsigned short* Ws = Wth + (size_t)half * COLS * 128;
#pragma unroll
      for (int it = 0; it < COLS / 16; ++it) {
        int c = it * 16 + (tid >> 4);
        int cb = (tid & 15) << 4;
        int sb = cb ^ ((c & 7) << 4);
        const char* src = (const char*)(Ws + (size_t)c * 128) + sb;
        char* dst = (char*)wS + it * 4096 + (tid >> 6) * 1024;
        GLOAD_LDS16(src, dst);
      }
      asm volatile("s_waitcnt vmcnt(0)" ::: "memory");
      __syncthreads();
    }
#pragma unroll
    for (int ks = 0; ks < 4; ++ks) {
      int kb = ks * 64 + kg * 16;
      bf16x8 av[RF], bv[CF];
#pragma unroll
      for (int i = 0; i < RF; ++i) {
        int row = r0 + i * 16 + l15;
        av[i] = *(const bf16x8*)((const char*)aS + row * 256 + (kb ^ ((row & 7) << 4)));
      }
#pragma unroll
      for (int j = 0; j < CF; ++j) {
        int c = c0 + j * 16 + l15;
        bv[j] = *(const bf16x8*)((const char*)wS + c * 256 + (kb ^ ((c & 7) << 4)));
      }
#pragma unroll
      for (int i = 0; i < RF; ++i)
#pragma unroll
        for (int j = 0; j < CF; ++j)
          acc[i][j] = __builtin_amdgcn_mfma_f32_16x16x32_bf16(av[i], bv[j], acc[i][j], 0, 0, 0);
    }
  }

  if (EPI == 3) {
    bool leftHalf = (c0 == 0);
    unsigned short* R3b = (unsigned short*)outF;
    float bcol[CF];
#pragma unroll
    for (int j = 0; j < CF; ++j) {
      int c = c0 + j * 16 + l15;
      bcol[j] = (!leftHalf && (c - 64) < NCLASS) ? bias[c - 64] : 0.f;
    }
#pragma unroll
    for (int i = 0; i < RF; ++i) {
#pragma unroll
      for (int r = 0; r < 4; ++r) {
        int row = rowBase + r0 + i * 16 + kg * 4 + r;
        if (row >= n) continue;
#pragma unroll
        for (int j = 0; j < CF; ++j) {
          int c = c0 + j * 16 + l15;
          if (leftHalf) {
            outB[(size_t)row * 64 + c] = f2bf(acc[i][j][r]);
          } else {
            R3b[(size_t)row * 64 + (c - 64)] = f2bf(acc[i][j][r] + bcol[j]);
          }
        }
      }
    }
  } else {
    float bcol[CF];
#pragma unroll
    for (int j = 0; j < CF; ++j) bcol[j] = bias[c0 + j * 16 + l15];
#pragma unroll
    for (int i = 0; i < RF; ++i) {
#pragma unroll
      for (int r = 0; r < 4; ++r) {
        int row = rowBase + r0 + i * 16 + kg * 4 + r;
        if (row >= n) continue;
#pragma unroll
        for (int j = 0; j < CF; ++j) {
          float v = fmaxf(acc[i][j][r] + bcol[j], 0.f);
          int c = c0 + j * 16 + l15;
          outB[(size_t)row * 128 + c] = f2bf(v);
          if (EPI == 1) outF[(size_t)row * 128 + c] = v;
          if (EPI == 0) {
            unsigned pk = __builtin_amdgcn_cvt_pk_fp8_f32(v, v, 0, false);
            ((unsigned char*)outF)[(size_t)row * 128 + c] = (unsigned char)(pk & 0xff);
          }
        }
      }
    }
  }
}

// ------- layer-3: width-64 bf16 mean agg + root + log_softmax, 16 lanes/row -------
// uint2 (4 bf16) per lane; 4 edge-groups; 4 acc; 2 group-reduce rounds.
__global__ void k_agg3ls(const char* __restrict__ Y3, const char* __restrict__ R3,
                         const int* __restrict__ off, const int* __restrict__ col, int n,
                         float* __restrict__ out) {
  int wid = (blockIdx.x * blockDim.x + threadIdx.x) >> 6;
  int lane = threadIdx.x & 63;
  if (wid >= n) return;
  int g = lane >> 4, q = lane & 15;
  unsigned qb = (unsigned)q << 3;  // 8 B = 4 bf16
  int s = off[wid], e = off[wid + 1];
  float acc[4];
#pragma unroll
  for (int t = 0; t < 4; ++t) acc[t] = 0.f;
  int e1 = e - 1;
  for (int j = s; j < e; j += 8) {
    int i0 = j + g, i1 = i0 + 4;
    int c0 = NTL(&col[min(i0, e1)]);
    int c1 = NTL(&col[min(i1, e1)]);
    float s0 = (i0 < e) ? 1.f : 0.f;
    float s1 = (i1 < e) ? 1.f : 0.f;
    uint2 u0 = *(const uint2*)(Y3 + (((unsigned)c0 << 7) + qb));
    uint2 u1 = *(const uint2*)(Y3 + (((unsigned)c1 << 7) + qb));
    ACC4(u0, s0);
    ACC4(u1, s1);
  }
#pragma unroll
  for (int t = 0; t < 4; ++t) {
    acc[t] += __shfl_xor(acc[t], 16);
    acc[t] += __shfl_xor(acc[t], 32);
  }
  float inv = 1.0f / fmaxf((float)(e - s), 1.0f);
  uint2 ur = *(const uint2*)(R3 + (((unsigned)wid << 7) + qb));
  float v[4];
  v[0] = fmaf(acc[0], inv, bflo(ur.x));
  v[1] = fmaf(acc[1], inv, bfhi(ur.x));
  v[2] = fmaf(acc[2], inv, bflo(ur.y));
  v[3] = fmaf(acc[3], inv, bfhi(ur.y));
  bool valid = q < 10;  // cols q*4..q*4+3 < 40
  float m = -INFINITY;
  if (valid) m = fmaxf(fmaxf(v[0], v[1]), fmaxf(v[2], v[3]));
  m = fmaxf(m, __shfl_xor(m, 1));
  m = fmaxf(m, __shfl_xor(m, 2));
  m = fmaxf(m, __shfl_xor(m, 4));
  m = fmaxf(m, __shfl_xor(m, 8));
  float sum = 0.f;
  if (valid)
    sum = expf(v[0] - m) + expf(v[1] - m) + expf(v[2] - m) + expf(v[3] - m);
  sum += __shfl_xor(sum, 1);
  sum += __shfl_xor(sum, 2);
  sum += __shfl_xor(sum, 4);
  sum += __shfl_xor(sum, 8);
  float ls = logf(sum);
  if (g == 0 && valid) {
    float4 o = make_float4(v[0] - m - ls, v[1] - m - ls, v[2] - m - ls, v[3] - m - ls);
    *(float4*)(out + (size_t)wid * NCLASS + q * 4) = o;
  }
}

extern "C" void kernel_launch(void* const* d_in, const int* in_sizes, int n_in,
                              void* d_out, int out_size, void* d_ws, size_t ws_size,
                              hipStream_t stream) {
  const float* x = (const float*)d_in[0];
  const int* ei = (const int*)d_in[1];
  const float* W1l = (const float*)d_in[2];
  const float* b1 = (const float*)d_in[3];
  const float* W1r = (const float*)d_in[4];
  const float* W2l = (const float*)d_in[5];
  const float* b2 = (const float*)d_in[6];
  const float* W2r = (const float*)d_in[7];
  const float* W3l = (const float*)d_in[8];
  const float* b3 = (const float*)d_in[9];
  const float* W3r = (const float*)d_in[10];

  int N = in_sizes[0] / 128;
  int E = in_sizes[1] / 2;
  const int* src = ei;
  const int* dst = ei + E;
  int NSB = (N + 511) >> 9;  // <= 256 for N <= 131072
  int nbB = (E + BEDG4 - 1) / BEDG4;

  char* wptr = (char*)d_ws;
  auto alloc = [&](size_t bytes) {
    void* p = (void*)wptr;
    wptr += (bytes + 255) & ~(size_t)255;
    return p;
  };
  int* off = (int*)alloc((size_t)(N + 1) * 4);
  int* col = (int*)alloc((size_t)E * 4);
  int* bcnt = (int*)alloc((size_t)nbB * 256 * 4);
  int* tot = (int*)alloc(256 * 4);
  int* base2 = (int*)alloc(257 * 4);
  unsigned short* Wth1 = (unsigned short*)alloc(32768 * 2);
  unsigned short* Wth2 = (unsigned short*)alloc(32768 * 2);
  unsigned short* Wth3 = (unsigned short*)alloc(16384 * 2);
  unsigned short* xb = (unsigned short*)alloc((size_t)N * 128 * 2);
  unsigned short* mb = (unsigned short*)alloc((size_t)N * 128 * 2);
  unsigned short* h1 = (unsigned short*)alloc((size_t)N * 128 * 2);
  unsigned short* h2 = (unsigned short*)alloc((size_t)N * 128 * 2);
  unsigned char* xq = (unsigned char*)alloc((size_t)N * 128);
  unsigned char* h1q = (unsigned char*)alloc((size_t)N * 128);

  float* outLS = (float*)d_out;                     // [N][40]
  float* emb = (float*)d_out + (size_t)N * NCLASS;  // [N][128]

  // Aliases (lifetimes disjoint on the stream):
  int* ebuf2 = (int*)h2;     // E ints; dead before gemm2 writes h2
  unsigned short* Y3 = mb;   // bf16 [N][64]; mb dead after gemm2
  unsigned short* R3b = h1;  // bf16 [N][64]; h1 dead after gemm2

  // CSR build: single-level counting sort by 512-node range, no global atomics
  k_bcountF<<<nbB, 256, 0, stream>>>(dst, E, bcnt);
  k_bscanF<<<NSB, 256, 0, stream>>>(bcnt, nbB, tot);
  k_baseF<<<1, 256, 0, stream>>>(tot, NSB, N, E, base2, off);
  k_placeF<<<nbB, 256, 0, stream>>>(dst, src, E, bcnt, base2, ebuf2);
  k_csrF<<<NSB, 256, 0, stream>>>(ebuf2, base2, tot, N, off, col);

  int n8 = N * 16;
  k_cast<<<(n8 + 255) / 256, 256, 0, stream>>>((const float4*)x, (uint4*)xb, (uint2*)xq,
                                               n8);
  k_prepw<<<(81920 + 255) / 256, 256, 0, stream>>>(W1l, W1r, W2l, W2r, W3l, W3r, Wth1,
                                                   Wth2, Wth3);

  int ab = (N * 64 + 255) / 256;
  int gb = (N + 127) / 128;

  // layer 1: fp8 gather of xq -> mb; gemm writes h1 bf16 + h1q fp8
  k_aggq<<<ab, 256, 0, stream>>>((const char*)xq, off, col, N, (uint4*)mb);
  k_gemm_mfma<128, 2, 0><<<gb, 256, 0, stream>>>(mb, xb, Wth1, b1, N, (float*)h1q, h1);
  // layer 2: fp8 gather of h1q -> mb; gemm writes emb f32 + h2 bf16
  k_aggq<<<ab, 256, 0, stream>>>((const char*)h1q, off, col, N, (uint4*)mb);
  k_gemm_mfma<128, 2, 1><<<gb, 256, 0, stream>>>(mb, h1, Wth2, b2, N, emb, h2);
  // layer 3: project first (Y3 = h2@W3l bf16, R3 = h2@W3r + b3 bf16), then
  // width-64 bf16 gather + fused root add + log_softmax
  k_gemm_mfma<128, 1, 3><<<gb, 256, 0, stream>>>(h2, nullptr, Wth3, b3, N, (float*)R3b, Y3);
  k_agg3ls<<<ab, 256, 0, stream>>>((const char*)Y3, (const char*)R3b, off, col, N, outLS);
}

// Round 11
// 298.573 us; speedup vs baseline: 1.0165x; 1.0165x over previous
//
#include <hip/hip_runtime.h>
#include <math.h>

#define NCLASS 40
#define BEDG4 4096  // edges per chunk block in CSR build
#define CAP 24576   // LDS col-staging capacity per 512-node sub-bucket

typedef float f32x4 __attribute__((ext_vector_type(4)));
typedef float f32x2 __attribute__((ext_vector_type(2)));
typedef __bf16 bf16x8 __attribute__((ext_vector_type(8)));

typedef __attribute__((address_space(1))) const void gv_t;
typedef __attribute__((address_space(3))) void lv_t;
#define GLOAD_LDS16(g, l) __builtin_amdgcn_global_load_lds((gv_t*)(g), (lv_t*)(l), 16, 0, 0)
#define NTL(p) __builtin_nontemporal_load(p)

__device__ inline unsigned short f2bf(float f) {
  unsigned u = __float_as_uint(f);
  unsigned r = (u + 0x7fff + ((u >> 16) & 1)) >> 16;
  return (unsigned short)r;
}
__device__ inline float bflo(unsigned v) { return __uint_as_float(v << 16); }
__device__ inline float bfhi(unsigned v) { return __uint_as_float(v & 0xffff0000u); }

// decode 8 fp8 (one uint2) and accumulate with scale
#define ACCQ2(u, sc)                                                  \
  do {                                                                \
    f32x2 p_;                                                         \
    p_ = __builtin_amdgcn_cvt_pk_f32_fp8(u.x, false);                 \
    acc[0] = fmaf(p_.x, sc, acc[0]); acc[1] = fmaf(p_.y, sc, acc[1]); \
    p_ = __builtin_amdgcn_cvt_pk_f32_fp8(u.x, true);                  \
    acc[2] = fmaf(p_.x, sc, acc[2]); acc[3] = fmaf(p_.y, sc, acc[3]); \
    p_ = __builtin_amdgcn_cvt_pk_f32_fp8(u.y, false);                 \
    acc[4] = fmaf(p_.x, sc, acc[4]); acc[5] = fmaf(p_.y, sc, acc[5]); \
    p_ = __builtin_amdgcn_cvt_pk_f32_fp8(u.y, true);                  \
    acc[6] = fmaf(p_.x, sc, acc[6]); acc[7] = fmaf(p_.y, sc, acc[7]); \
  } while (0)

// decode 8 bf16 (one uint4) and accumulate with scale
#define ACC8(u, sc)                     \
  acc[0] = fmaf(bflo(u.x), sc, acc[0]); \
  acc[1] = fmaf(bfhi(u.x), sc, acc[1]); \
  acc[2] = fmaf(bflo(u.y), sc, acc[2]); \
  acc[3] = fmaf(bfhi(u.y), sc, acc[3]); \
  acc[4] = fmaf(bflo(u.z), sc, acc[4]); \
  acc[5] = fmaf(bfhi(u.z), sc, acc[5]); \
  acc[6] = fmaf(bflo(u.w), sc, acc[6]); \
  acc[7] = fmaf(bfhi(u.w), sc, acc[7]);

// ============ CSR build: single-level counting sort by 512-node range =========
__global__ __launch_bounds__(256) void k_bcountF(const int* __restrict__ dst, int E,
                                                 int* __restrict__ bcnt) {
  __shared__ int lc[256];
  int k = blockIdx.x;
  int tid = threadIdx.x;
  lc[tid] = 0;
  __syncthreads();
  int lo = k * BEDG4, hi = min(lo + BEDG4, E);
  for (int i = lo + tid; i < hi; i += 256) atomicAdd(&lc[NTL(&dst[i]) >> 9], 1);
  __syncthreads();
  bcnt[k * 256 + tid] = lc[tid];
}

__global__ __launch_bounds__(256) void k_bscanF(int* __restrict__ bcnt, int nbB,
                                                int* __restrict__ tot) {
  __shared__ int tmp[256];
  __shared__ int carryS;
  int b = blockIdx.x;
  int tid = threadIdx.x;
  if (tid == 0) carryS = 0;
  __syncthreads();
  for (int c0 = 0; c0 < nbB; c0 += 256) {
    int idx = c0 + tid;
    int v = (idx < nbB) ? bcnt[idx * 256 + b] : 0;
    tmp[tid] = v;
    __syncthreads();
    for (int d = 1; d < 256; d <<= 1) {
      int t = (tid >= d) ? tmp[tid - d] : 0;
      __syncthreads();
      tmp[tid] += t;
      __syncthreads();
    }
    if (idx < nbB) bcnt[idx * 256 + b] = carryS + tmp[tid] - v;
    __syncthreads();
    if (tid == 255) carryS += tmp[255];
    __syncthreads();
  }
  if (tid == 0) tot[b] = carryS;
}

__global__ __launch_bounds__(256) void k_baseF(const int* __restrict__ tot, int NSB,
                                               int N, int E, int* __restrict__ base2,
                                               int* __restrict__ off) {
  __shared__ int tmp[256];
  int tid = threadIdx.x;
  int v = (tid < NSB) ? tot[tid] : 0;
  tmp[tid] = v;
  __syncthreads();
  for (int d = 1; d < 256; d <<= 1) {
    int t = (tid >= d) ? tmp[tid - d] : 0;
    __syncthreads();
    tmp[tid] += t;
    __syncthreads();
  }
  base2[tid] = tmp[tid] - v;
  if (tid == 0) {
    base2[NSB] = E;
    off[N] = E;
  }
}

__global__ __launch_bounds__(256) void k_placeF(const int* __restrict__ dst,
                                                const int* __restrict__ src, int E,
                                                const int* __restrict__ bcnt,
                                                const int* __restrict__ base2,
                                                int* __restrict__ ebuf2) {
  __shared__ int lb[256];
  int k = blockIdx.x;
  int tid = threadIdx.x;
  lb[tid] = base2[tid] + bcnt[k * 256 + tid];
  __syncthreads();
  int lo = k * BEDG4, hi = min(lo + BEDG4, E);
  for (int i = lo + tid; i < hi; i += 256) {
    int d = NTL(&dst[i]);
    int s = NTL(&src[i]);
    int pos = atomicAdd(&lb[d >> 9], 1);
    ebuf2[pos] = (int)(((unsigned)(d & 511) << 17) | (unsigned)s);
  }
}

__global__ __launch_bounds__(256) void k_csrF(const int* __restrict__ ebuf2,
                                              const int* __restrict__ base2,
                                              const int* __restrict__ tot, int N,
                                              int* __restrict__ off,
                                              int* __restrict__ col) {
  __shared__ int cnt[512];
  __shared__ int cur[512];
  __shared__ int tmp[256];
  __shared__ int stage[CAP];
  int sb = blockIdx.x;
  int tid = threadIdx.x;
  int node0 = sb << 9;
  if (node0 >= N) return;
  int nn = min(512, N - node0);
  int lo = base2[sb];
  int t2 = tot[sb];

  cnt[tid] = 0;
  cnt[tid + 256] = 0;
  __syncthreads();
  for (int i = lo + tid; i < lo + t2; i += 256)
    atomicAdd(&cnt[(((unsigned)ebuf2[i]) >> 17) & 511], 1);
  __syncthreads();

  int v0 = cnt[2 * tid], v1 = cnt[2 * tid + 1];
  int s = v0 + v1;
  tmp[tid] = s;
  __syncthreads();
  for (int d = 1; d < 256; d <<= 1) {
    int t = (tid >= d) ? tmp[tid - d] : 0;
    __syncthreads();
    tmp[tid] += t;
    __syncthreads();
  }
  int excl = tmp[tid] - s;
  cnt[2 * tid] = excl;
  cnt[2 * tid + 1] = excl + v0;
  cur[2 * tid] = excl;
  cur[2 * tid + 1] = excl + v0;
  __syncthreads();

  for (int i = tid; i < nn; i += 256) off[node0 + i] = lo + cnt[i];

  if (t2 <= CAP) {
    for (int i = lo + tid; i < lo + t2; i += 256) {
      unsigned pk = (unsigned)ebuf2[i];
      int pos = atomicAdd(&cur[(pk >> 17) & 511], 1);
      stage[pos] = (int)(pk & 0x1FFFFu);
    }
    __syncthreads();
    for (int i = tid; i < t2; i += 256) col[lo + i] = stage[i];
  } else {
    for (int i = lo + tid; i < lo + t2; i += 256) {
      unsigned pk = (unsigned)ebuf2[i];
      int pos = atomicAdd(&cur[(pk >> 17) & 511], 1);
      col[lo + pos] = (int)(pk & 0x1FFFFu);
    }
  }
}

// ---------------- casts / weight prep ----------------
__global__ void k_cast(const float4* __restrict__ x, uint4* __restrict__ xb,
                       uint2* __restrict__ xq, int n8) {
  int i = blockIdx.x * blockDim.x + threadIdx.x;
  if (i >= n8) return;
  float4 a = x[i * 2], b = x[i * 2 + 1];
  uint4 o;
  o.x = (unsigned)f2bf(a.x) | ((unsigned)f2bf(a.y) << 16);
  o.y = (unsigned)f2bf(a.z) | ((unsigned)f2bf(a.w) << 16);
  o.z = (unsigned)f2bf(b.x) | ((unsigned)f2bf(b.y) << 16);
  o.w = (unsigned)f2bf(b.z) | ((unsigned)f2bf(b.w) << 16);
  xb[i] = o;
  unsigned lo = __builtin_amdgcn_cvt_pk_fp8_f32(a.x, a.y, 0, false);
  lo = __builtin_amdgcn_cvt_pk_fp8_f32(a.z, a.w, lo, true);
  unsigned hi = __builtin_amdgcn_cvt_pk_fp8_f32(b.x, b.y, 0, false);
  hi = __builtin_amdgcn_cvt_pk_fp8_f32(b.z, b.w, hi, true);
  xq[i] = make_uint2(lo, hi);
}

// Wth layout: [half][COLS][128] bf16. half0=Wl^T, half1=Wr^T.
__global__ void k_prepw(const float* __restrict__ W1l, const float* __restrict__ W1r,
                        const float* __restrict__ W2l, const float* __restrict__ W2r,
                        const float* __restrict__ W3l, const float* __restrict__ W3r,
                        unsigned short* __restrict__ Wth1, unsigned short* __restrict__ Wth2,
                        unsigned short* __restrict__ Wth3) {
  int idx = blockIdx.x * blockDim.x + threadIdx.x;
  if (idx < 32768) {
    int h = idx >> 14, c = (idx >> 7) & 127, k = idx & 127;
    const float* W = h ? W1r : W1l;
    Wth1[idx] = f2bf(W[k * 128 + c]);
  } else if (idx < 65536) {
    int j = idx - 32768;
    int h = j >> 14, c = (j >> 7) & 127, k = j & 127;
    const float* W = h ? W2r : W2l;
    Wth2[j] = f2bf(W[k * 128 + c]);
  } else if (idx < 65536 + 16384) {
    int j = idx - 65536;
    int h = j >> 13, c = (j >> 7) & 63, k = j & 127;
    float v = 0.f;
    if (c < NCLASS) v = (h ? W3r : W3l)[k * NCLASS + c];
    Wth3[j] = f2bf(v);
  }
}

// ------- mean aggregation, width 128, fp8 rows: 16 lanes/row, uint2/lane -------
// 4 edge-groups, 2 loads in flight (8 edges/iter); 8 acc; 2 shuffle rounds.
__global__ void k_aggq(const char* __restrict__ Xq, const int* __restrict__ off,
                       const int* __restrict__ col, int n, uint4* __restrict__ out) {
  int wid = (blockIdx.x * blockDim.x + threadIdx.x) >> 6;
  int lane = threadIdx.x & 63;
  if (wid >= n) return;
  int g = lane >> 4, q = lane & 15;
  unsigned qb = (unsigned)q << 3;  // 8 B per lane
  int s = off[wid], e = off[wid + 1];
  float acc[8];
#pragma unroll
  for (int t = 0; t < 8; ++t) acc[t] = 0.f;
  int e1 = e - 1;
  for (int j = s; j < e; j += 8) {
    int i0 = j + g, i1 = i0 + 4;
    int c0 = NTL(&col[min(i0, e1)]);
    int c1 = NTL(&col[min(i1, e1)]);
    float s0 = (i0 < e) ? 1.f : 0.f;
    float s1 = (i1 < e) ? 1.f : 0.f;
    uint2 u0 = *(const uint2*)(Xq + (((unsigned)c0 << 7) + qb));
    uint2 u1 = *(const uint2*)(Xq + (((unsigned)c1 << 7) + qb));
    ACCQ2(u0, s0);
    ACCQ2(u1, s1);
  }
#pragma unroll
  for (int t = 0; t < 8; ++t) {
    acc[t] += __shfl_xor(acc[t], 16);
    acc[t] += __shfl_xor(acc[t], 32);
  }
  float inv = 1.0f / fmaxf((float)(e - s), 1.0f);
  if (lane < 16) {
    uint4 o;
    o.x = (unsigned)f2bf(acc[0] * inv) | ((unsigned)f2bf(acc[1] * inv) << 16);
    o.y = (unsigned)f2bf(acc[2] * inv) | ((unsigned)f2bf(acc[3] * inv) << 16);
    o.z = (unsigned)f2bf(acc[4] * inv) | ((unsigned)f2bf(acc[5] * inv) << 16);
    o.w = (unsigned)f2bf(acc[6] * inv) | ((unsigned)f2bf(acc[7] * inv) << 16);
    out[(size_t)wid * 16 + q] = o;
  }
}

// ---------------- MFMA GEMM ----------------
// EPI 0: relu -> outB bf16 [n][128] AND (fp8*)outF [n][128]
// EPI 1: relu -> outB bf16 [n][128] AND outF f32 [n][128]
// EPI 3: cols 0..63 -> outB bf16 [n][64] (Y3); cols 64..127 -> (bf16*)outF [n][64] (R3)
template <int COLS, int HALVES, int EPI>
__global__ __launch_bounds__(256) void k_gemm_mfma(
    const unsigned short* __restrict__ Aagg, const unsigned short* __restrict__ Aroot,
    const unsigned short* __restrict__ Wth, const float* __restrict__ bias, int n,
    float* __restrict__ outF, unsigned short* __restrict__ outB) {
  constexpr int RF = 4;
  constexpr int CF = 4;
  __shared__ unsigned short aS[128 * 128];
  __shared__ unsigned short wS[COLS * 128];
  int tid = threadIdx.x;
  int w = tid >> 6, lane = tid & 63, l15 = lane & 15, kg = lane >> 4;
  int rowBase = blockIdx.x * 128;
  int r0 = (w >> 1) * 64;
  int c0 = (w & 1) * 64;

  f32x4 acc[RF][CF];
#pragma unroll
  for (int i = 0; i < RF; ++i)
#pragma unroll
    for (int j = 0; j < CF; ++j) acc[i][j] = (f32x4){0.f, 0.f, 0.f, 0.f};

#pragma unroll
  for (int half = 0; half < HALVES; ++half) {
    if (half) __syncthreads();
    {
      const unsigned short* As = half ? Aroot : Aagg;
#pragma unroll
      for (int it = 0; it < 8; ++it) {
        int row = it * 16 + (tid >> 4);
        int g = rowBase + row;
        g = (g < n) ? g : (n - 1);
        int cb = (tid & 15) << 4;
        int sb = cb ^ ((row & 7) << 4);
        const char* src = (const char*)(As + (size_t)g * 128) + sb;
        char* dst = (char*)aS + it * 4096 + (tid >> 6) * 1024;
        GLOAD_LDS16(src, dst);
      }
      const unsigned short* Ws = Wth + (size_t)half * COLS * 128;
#pragma unroll
      for (int it = 0; it < COLS / 16; ++it) {
        int c = it * 16 + (tid >> 4);
        int cb = (tid & 15) << 4;
        int sb = cb ^ ((c & 7) << 4);
        const char* src = (const char*)(Ws + (size_t)c * 128) + sb;
        char* dst = (char*)wS + it * 4096 + (tid >> 6) * 1024;
        GLOAD_LDS16(src, dst);
      }
      asm volatile("s_waitcnt vmcnt(0)" ::: "memory");
      __syncthreads();
    }
#pragma unroll
    for (int ks = 0; ks < 4; ++ks) {
      int kb = ks * 64 + kg * 16;
      bf16x8 av[RF], bv[CF];
#pragma unroll
      for (int i = 0; i < RF; ++i) {
        int row = r0 + i * 16 + l15;
        av[i] = *(const bf16x8*)((const char*)aS + row * 256 + (kb ^ ((row & 7) << 4)));
      }
#pragma unroll
      for (int j = 0; j < CF; ++j) {
        int c = c0 + j * 16 + l15;
        bv[j] = *(const bf16x8*)((const char*)wS + c * 256 + (kb ^ ((c & 7) << 4)));
      }
#pragma unroll
      for (int i = 0; i < RF; ++i)
#pragma unroll
        for (int j = 0; j < CF; ++j)
          acc[i][j] = __builtin_amdgcn_mfma_f32_16x16x32_bf16(av[i], bv[j], acc[i][j], 0, 0, 0);
    }
  }

  if (EPI == 3) {
    bool leftHalf = (c0 == 0);
    unsigned short* R3b = (unsigned short*)outF;
    float bcol[CF];
#pragma unroll
    for (int j = 0; j < CF; ++j) {
      int c = c0 + j * 16 + l15;
      bcol[j] = (!leftHalf && (c - 64) < NCLASS) ? bias[c - 64] : 0.f;
    }
#pragma unroll
    for (int i = 0; i < RF; ++i) {
#pragma unroll
      for (int r = 0; r < 4; ++r) {
        int row = rowBase + r0 + i * 16 + kg * 4 + r;
        if (row >= n) continue;
#pragma unroll
        for (int j = 0; j < CF; ++j) {
          int c = c0 + j * 16 + l15;
          if (leftHalf) {
            outB[(size_t)row * 64 + c] = f2bf(acc[i][j][r]);
          } else {
            R3b[(size_t)row * 64 + (c - 64)] = f2bf(acc[i][j][r] + bcol[j]);
          }
        }
      }
    }
  } else {
    float bcol[CF];
#pragma unroll
    for (int j = 0; j < CF; ++j) bcol[j] = bias[c0 + j * 16 + l15];
#pragma unroll
    for (int i = 0; i < RF; ++i) {
#pragma unroll
      for (int r = 0; r < 4; ++r) {
        int row = rowBase + r0 + i * 16 + kg * 4 + r;
        if (row >= n) continue;
#pragma unroll
        for (int j = 0; j < CF; ++j) {
          float v = fmaxf(acc[i][j][r] + bcol[j], 0.f);
          int c = c0 + j * 16 + l15;
          outB[(size_t)row * 128 + c] = f2bf(v);
          if (EPI == 1) outF[(size_t)row * 128 + c] = v;
          if (EPI == 0) {
            unsigned pk = __builtin_amdgcn_cvt_pk_fp8_f32(v, v, 0, false);
            ((unsigned char*)outF)[(size_t)row * 128 + c] = (unsigned char)(pk & 0xff);
          }
        }
      }
    }
  }
}

// ------- layer-3: width-64 bf16 mean agg + root + log_softmax, 8 lanes/row -------
// uint4 (8 bf16) per lane; 8 edge-groups; 16 edges/iter; 8 acc; 3 reduce rounds.
__global__ void k_agg3ls(const char* __restrict__ Y3, const char* __restrict__ R3,
                         const int* __restrict__ off, const int* __restrict__ col, int n,
                         float* __restrict__ out) {
  int wid = (blockIdx.x * blockDim.x + threadIdx.x) >> 6;
  int lane = threadIdx.x & 63;
  if (wid >= n) return;
  int g = lane >> 3, q = lane & 7;
  unsigned qb = (unsigned)q << 4;
  int s = off[wid], e = off[wid + 1];
  float acc[8];
#pragma unroll
  for (int t = 0; t < 8; ++t) acc[t] = 0.f;
  int e1 = e - 1;
  for (int j = s; j < e; j += 16) {
    int i0 = j + g, i1 = i0 + 8;
    int c0 = NTL(&col[min(i0, e1)]);
    int c1 = NTL(&col[min(i1, e1)]);
    float s0 = (i0 < e) ? 1.f : 0.f;
    float s1 = (i1 < e) ? 1.f : 0.f;
    uint4 u0 = *(const uint4*)(Y3 + (((unsigned)c0 << 7) + qb));
    uint4 u1 = *(const uint4*)(Y3 + (((unsigned)c1 << 7) + qb));
    ACC8(u0, s0);
    ACC8(u1, s1);
  }
#pragma unroll
  for (int t = 0; t < 8; ++t) {
    acc[t] += __shfl_xor(acc[t], 8);
    acc[t] += __shfl_xor(acc[t], 16);
    acc[t] += __shfl_xor(acc[t], 32);
  }
  float inv = 1.0f / fmaxf((float)(e - s), 1.0f);
  uint4 ur = *(const uint4*)(R3 + (((unsigned)wid << 7) + qb));
  float v[8];
  v[0] = fmaf(acc[0], inv, bflo(ur.x));
  v[1] = fmaf(acc[1], inv, bfhi(ur.x));
  v[2] = fmaf(acc[2], inv, bflo(ur.y));
  v[3] = fmaf(acc[3], inv, bfhi(ur.y));
  v[4] = fmaf(acc[4], inv, bflo(ur.z));
  v[5] = fmaf(acc[5], inv, bfhi(ur.z));
  v[6] = fmaf(acc[6], inv, bflo(ur.w));
  v[7] = fmaf(acc[7], inv, bfhi(ur.w));
  bool valid = q < 5;  // cols q*8..q*8+7 < 40
  float m = -INFINITY;
  if (valid) {
#pragma unroll
    for (int t = 0; t < 8; ++t) m = fmaxf(m, v[t]);
  }
  m = fmaxf(m, __shfl_xor(m, 1));
  m = fmaxf(m, __shfl_xor(m, 2));
  m = fmaxf(m, __shfl_xor(m, 4));
  float sum = 0.f;
  if (valid) {
#pragma unroll
    for (int t = 0; t < 8; ++t) sum += expf(v[t] - m);
  }
  sum += __shfl_xor(sum, 1);
  sum += __shfl_xor(sum, 2);
  sum += __shfl_xor(sum, 4);
  float ls = logf(sum);
  if (lane < 5) {
    float4 o0 = make_float4(v[0] - m - ls, v[1] - m - ls, v[2] - m - ls, v[3] - m - ls);
    float4 o1 = make_float4(v[4] - m - ls, v[5] - m - ls, v[6] - m - ls, v[7] - m - ls);
    float* op = out + (size_t)wid * NCLASS + lane * 8;
    *(float4*)op = o0;
    *(float4*)(op + 4) = o1;
  }
}

extern "C" void kernel_launch(void* const* d_in, const int* in_sizes, int n_in,
                              void* d_out, int out_size, void* d_ws, size_t ws_size,
                              hipStream_t stream) {
  const float* x = (const float*)d_in[0];
  const int* ei = (const int*)d_in[1];
  const float* W1l = (const float*)d_in[2];
  const float* b1 = (const float*)d_in[3];
  const float* W1r = (const float*)d_in[4];
  const float* W2l = (const float*)d_in[5];
  const float* b2 = (const float*)d_in[6];
  const float* W2r = (const float*)d_in[7];
  const float* W3l = (const float*)d_in[8];
  const float* b3 = (const float*)d_in[9];
  const float* W3r = (const float*)d_in[10];

  int N = in_sizes[0] / 128;
  int E = in_sizes[1] / 2;
  const int* src = ei;
  const int* dst = ei + E;
  int NSB = (N + 511) >> 9;  // <= 256 for N <= 131072
  int nbB = (E + BEDG4 - 1) / BEDG4;

  char* wptr = (char*)d_ws;
  auto alloc = [&](size_t bytes) {
    void* p = (void*)wptr;
    wptr += (bytes + 255) & ~(size_t)255;
    return p;
  };
  int* off = (int*)alloc((size_t)(N + 1) * 4);
  int* col = (int*)alloc((size_t)E * 4);
  int* bcnt = (int*)alloc((size_t)nbB * 256 * 4);
  int* tot = (int*)alloc(256 * 4);
  int* base2 = (int*)alloc(257 * 4);
  unsigned short* Wth1 = (unsigned short*)alloc(32768 * 2);
  unsigned short* Wth2 = (unsigned short*)alloc(32768 * 2);
  unsigned short* Wth3 = (unsigned short*)alloc(16384 * 2);
  unsigned short* xb = (unsigned short*)alloc((size_t)N * 128 * 2);
  unsigned short* mb = (unsigned short*)alloc((size_t)N * 128 * 2);
  unsigned short* h1 = (unsigned short*)alloc((size_t)N * 128 * 2);
  unsigned short* h2 = (unsigned short*)alloc((size_t)N * 128 * 2);
  unsigned char* xq = (unsigned char*)alloc((size_t)N * 128);
  unsigned char* h1q = (unsigned char*)alloc((size_t)N * 128);

  float* outLS = (float*)d_out;                     // [N][40]
  float* emb = (float*)d_out + (size_t)N * NCLASS;  // [N][128]

  // Aliases (lifetimes disjoint on the stream):
  int* ebuf2 = (int*)h2;     // E ints; dead before gemm2 writes h2
  unsigned short* Y3 = mb;   // bf16 [N][64]; mb dead after gemm2
  unsigned short* R3b = h1;  // bf16 [N][64]; h1 dead after gemm2

  // CSR build: single-level counting sort by 512-node range, no global atomics
  k_bcountF<<<nbB, 256, 0, stream>>>(dst, E, bcnt);
  k_bscanF<<<NSB, 256, 0, stream>>>(bcnt, nbB, tot);
  k_baseF<<<1, 256, 0, stream>>>(tot, NSB, N, E, base2, off);
  k_placeF<<<nbB, 256, 0, stream>>>(dst, src, E, bcnt, base2, ebuf2);
  k_csrF<<<NSB, 256, 0, stream>>>(ebuf2, base2, tot, N, off, col);

  int n8 = N * 16;
  k_cast<<<(n8 + 255) / 256, 256, 0, stream>>>((const float4*)x, (uint4*)xb, (uint2*)xq,
                                               n8);
  k_prepw<<<(81920 + 255) / 256, 256, 0, stream>>>(W1l, W1r, W2l, W2r, W3l, W3r, Wth1,
                                                   Wth2, Wth3);

  int ab = (N * 64 + 255) / 256;
  int gb = (N + 127) / 128;

  // layer 1: fp8 gather of xq -> mb; gemm writes h1 bf16 + h1q fp8
  k_aggq<<<ab, 256, 0, stream>>>((const char*)xq, off, col, N, (uint4*)mb);
  k_gemm_mfma<128, 2, 0><<<gb, 256, 0, stream>>>(mb, xb, Wth1, b1, N, (float*)h1q, h1);
  // layer 2: fp8 gather of h1q -> mb; gemm writes emb f32 + h2 bf16
  k_aggq<<<ab, 256, 0, stream>>>((const char*)h1q, off, col, N, (uint4*)mb);
  k_gemm_mfma<128, 2, 1><<<gb, 256, 0, stream>>>(mb, h1, Wth2, b2, N, emb, h2);
  // layer 3: project first (Y3 = h2@W3l bf16, R3 = h2@W3r + b3 bf16), then
  // width-64 bf16 gather + fused root add + log_softmax
  k_gemm_mfma<128, 1, 3><<<gb, 256, 0, stream>>>(h2, nullptr, Wth3, b3, N, (float*)R3b, Y3);
  k_agg3ls<<<ab, 256, 0, stream>>>((const char*)Y3, (const char*)R3b, off, col, N, outLS);
}

// Round 12
// 278.428 us; speedup vs baseline: 1.0900x; 1.0724x over previous
//
#include <hip/hip_runtime.h>
#include <math.h>

#define NCLASS 40
#define BEDG4 4096  // edges per chunk block in CSR build
#define CAP 24576   // LDS col-staging capacity per 512-node sub-bucket

typedef float f32x4 __attribute__((ext_vector_type(4)));
typedef float f32x2 __attribute__((ext_vector_type(2)));
typedef __bf16 bf16x8 __attribute__((ext_vector_type(8)));

typedef __attribute__((address_space(1))) const void gv_t;
typedef __attribute__((address_space(3))) void lv_t;
#define GLOAD_LDS16(g, l) __builtin_amdgcn_global_load_lds((gv_t*)(g), (lv_t*)(l), 16, 0, 0)
#define NTL(p) __builtin_nontemporal_load(p)

__device__ inline unsigned short f2bf(float f) {
  unsigned u = __float_as_uint(f);
  unsigned r = (u + 0x7fff + ((u >> 16) & 1)) >> 16;
  return (unsigned short)r;
}
__device__ inline float bflo(unsigned v) { return __uint_as_float(v << 16); }
__device__ inline float bfhi(unsigned v) { return __uint_as_float(v & 0xffff0000u); }

// decode 8 fp8 (one uint2) and accumulate with scale
#define ACCQ2(u, sc)                                                  \
  do {                                                                \
    f32x2 p_;                                                         \
    p_ = __builtin_amdgcn_cvt_pk_f32_fp8(u.x, false);                 \
    acc[0] = fmaf(p_.x, sc, acc[0]); acc[1] = fmaf(p_.y, sc, acc[1]); \
    p_ = __builtin_amdgcn_cvt_pk_f32_fp8(u.x, true);                  \
    acc[2] = fmaf(p_.x, sc, acc[2]); acc[3] = fmaf(p_.y, sc, acc[3]); \
    p_ = __builtin_amdgcn_cvt_pk_f32_fp8(u.y, false);                 \
    acc[4] = fmaf(p_.x, sc, acc[4]); acc[5] = fmaf(p_.y, sc, acc[5]); \
    p_ = __builtin_amdgcn_cvt_pk_f32_fp8(u.y, true);                  \
    acc[6] = fmaf(p_.x, sc, acc[6]); acc[7] = fmaf(p_.y, sc, acc[7]); \
  } while (0)

// decode 8 bf16 (one uint4) and accumulate with scale
#define ACC8(u, sc)                     \
  acc[0] = fmaf(bflo(u.x), sc, acc[0]); \
  acc[1] = fmaf(bfhi(u.x), sc, acc[1]); \
  acc[2] = fmaf(bflo(u.y), sc, acc[2]); \
  acc[3] = fmaf(bfhi(u.y), sc, acc[3]); \
  acc[4] = fmaf(bflo(u.z), sc, acc[4]); \
  acc[5] = fmaf(bfhi(u.z), sc, acc[5]); \
  acc[6] = fmaf(bflo(u.w), sc, acc[6]); \
  acc[7] = fmaf(bfhi(u.w), sc, acc[7]);

// ============ CSR build: single-level counting sort by 512-node range =========
__global__ __launch_bounds__(256) void k_bcountF(const int* __restrict__ dst, int E,
                                                 int* __restrict__ bcnt) {
  __shared__ int lc[256];
  int k = blockIdx.x;
  int tid = threadIdx.x;
  lc[tid] = 0;
  __syncthreads();
  int lo = k * BEDG4, hi = min(lo + BEDG4, E);
  for (int i = lo + tid; i < hi; i += 256) atomicAdd(&lc[NTL(&dst[i]) >> 9], 1);
  __syncthreads();
  bcnt[k * 256 + tid] = lc[tid];
}

__global__ __launch_bounds__(256) void k_bscanF(int* __restrict__ bcnt, int nbB,
                                                int* __restrict__ tot) {
  __shared__ int tmp[256];
  __shared__ int carryS;
  int b = blockIdx.x;
  int tid = threadIdx.x;
  if (tid == 0) carryS = 0;
  __syncthreads();
  for (int c0 = 0; c0 < nbB; c0 += 256) {
    int idx = c0 + tid;
    int v = (idx < nbB) ? bcnt[idx * 256 + b] : 0;
    tmp[tid] = v;
    __syncthreads();
    for (int d = 1; d < 256; d <<= 1) {
      int t = (tid >= d) ? tmp[tid - d] : 0;
      __syncthreads();
      tmp[tid] += t;
      __syncthreads();
    }
    if (idx < nbB) bcnt[idx * 256 + b] = carryS + tmp[tid] - v;
    __syncthreads();
    if (tid == 255) carryS += tmp[255];
    __syncthreads();
  }
  if (tid == 0) tot[b] = carryS;
}

__global__ __launch_bounds__(256) void k_baseF(const int* __restrict__ tot, int NSB,
                                               int N, int E, int* __restrict__ base2,
                                               int* __restrict__ off) {
  __shared__ int tmp[256];
  int tid = threadIdx.x;
  int v = (tid < NSB) ? tot[tid] : 0;
  tmp[tid] = v;
  __syncthreads();
  for (int d = 1; d < 256; d <<= 1) {
    int t = (tid >= d) ? tmp[tid - d] : 0;
    __syncthreads();
    tmp[tid] += t;
    __syncthreads();
  }
  base2[tid] = tmp[tid] - v;
  if (tid == 0) {
    base2[NSB] = E;
    off[N] = E;
  }
}

__global__ __launch_bounds__(256) void k_placeF(const int* __restrict__ dst,
                                                const int* __restrict__ src, int E,
                                                const int* __restrict__ bcnt,
                                                const int* __restrict__ base2,
                                                int* __restrict__ ebuf2) {
  __shared__ int lb[256];
  int k = blockIdx.x;
  int tid = threadIdx.x;
  lb[tid] = base2[tid] + bcnt[k * 256 + tid];
  __syncthreads();
  int lo = k * BEDG4, hi = min(lo + BEDG4, E);
  for (int i = lo + tid; i < hi; i += 256) {
    int d = NTL(&dst[i]);
    int s = NTL(&src[i]);
    int pos = atomicAdd(&lb[d >> 9], 1);
    ebuf2[pos] = (int)(((unsigned)(d & 511) << 17) | (unsigned)s);
  }
}

__global__ __launch_bounds__(256) void k_csrF(const int* __restrict__ ebuf2,
                                              const int* __restrict__ base2,
                                              const int* __restrict__ tot, int N,
                                              int* __restrict__ off,
                                              int* __restrict__ col) {
  __shared__ int cnt[512];
  __shared__ int cur[512];
  __shared__ int tmp[256];
  __shared__ int stage[CAP];
  int sb = blockIdx.x;
  int tid = threadIdx.x;
  int node0 = sb << 9;
  if (node0 >= N) return;
  int nn = min(512, N - node0);
  int lo = base2[sb];
  int t2 = tot[sb];

  cnt[tid] = 0;
  cnt[tid + 256] = 0;
  __syncthreads();
  for (int i = lo + tid; i < lo + t2; i += 256)
    atomicAdd(&cnt[(((unsigned)ebuf2[i]) >> 17) & 511], 1);
  __syncthreads();

  int v0 = cnt[2 * tid], v1 = cnt[2 * tid + 1];
  int s = v0 + v1;
  tmp[tid] = s;
  __syncthreads();
  for (int d = 1; d < 256; d <<= 1) {
    int t = (tid >= d) ? tmp[tid - d] : 0;
    __syncthreads();
    tmp[tid] += t;
    __syncthreads();
  }
  int excl = tmp[tid] - s;
  cnt[2 * tid] = excl;
  cnt[2 * tid + 1] = excl + v0;
  cur[2 * tid] = excl;
  cur[2 * tid + 1] = excl + v0;
  __syncthreads();

  for (int i = tid; i < nn; i += 256) off[node0 + i] = lo + cnt[i];

  if (t2 <= CAP) {
    for (int i = lo + tid; i < lo + t2; i += 256) {
      unsigned pk = (unsigned)ebuf2[i];
      int pos = atomicAdd(&cur[(pk >> 17) & 511], 1);
      stage[pos] = (int)(pk & 0x1FFFFu);
    }
    __syncthreads();
    for (int i = tid; i < t2; i += 256) col[lo + i] = stage[i];
  } else {
    for (int i = lo + tid; i < lo + t2; i += 256) {
      unsigned pk = (unsigned)ebuf2[i];
      int pos = atomicAdd(&cur[(pk >> 17) & 511], 1);
      col[lo + pos] = (int)(pk & 0x1FFFFu);
    }
  }
}

// ---------------- casts / weight prep ----------------
__global__ void k_cast(const float4* __restrict__ x, uint4* __restrict__ xb,
                       uint2* __restrict__ xq, int n8) {
  int i = blockIdx.x * blockDim.x + threadIdx.x;
  if (i >= n8) return;
  float4 a = x[i * 2], b = x[i * 2 + 1];
  uint4 o;
  o.x = (unsigned)f2bf(a.x) | ((unsigned)f2bf(a.y) << 16);
  o.y = (unsigned)f2bf(a.z) | ((unsigned)f2bf(a.w) << 16);
  o.z = (unsigned)f2bf(b.x) | ((unsigned)f2bf(b.y) << 16);
  o.w = (unsigned)f2bf(b.z) | ((unsigned)f2bf(b.w) << 16);
  xb[i] = o;
  unsigned lo = __builtin_amdgcn_cvt_pk_fp8_f32(a.x, a.y, 0, false);
  lo = __builtin_amdgcn_cvt_pk_fp8_f32(a.z, a.w, lo, true);
  unsigned hi = __builtin_amdgcn_cvt_pk_fp8_f32(b.x, b.y, 0, false);
  hi = __builtin_amdgcn_cvt_pk_fp8_f32(b.z, b.w, hi, true);
  xq[i] = make_uint2(lo, hi);
}

// Wth layout: [half][COLS][128] bf16. half0=Wl^T, half1=Wr^T.
__global__ void k_prepw(const float* __restrict__ W1l, const float* __restrict__ W1r,
                        const float* __restrict__ W2l, const float* __restrict__ W2r,
                        const float* __restrict__ W3l, const float* __restrict__ W3r,
                        unsigned short* __restrict__ Wth1, unsigned short* __restrict__ Wth2,
                        unsigned short* __restrict__ Wth3) {
  int idx = blockIdx.x * blockDim.x + threadIdx.x;
  if (idx < 32768) {
    int h = idx >> 14, c = (idx >> 7) & 127, k = idx & 127;
    const float* W = h ? W1r : W1l;
    Wth1[idx] = f2bf(W[k * 128 + c]);
  } else if (idx < 65536) {
    int j = idx - 32768;
    int h = j >> 14, c = (j >> 7) & 127, k = j & 127;
    const float* W = h ? W2r : W2l;
    Wth2[j] = f2bf(W[k * 128 + c]);
  } else if (idx < 65536 + 16384) {
    int j = idx - 65536;
    int h = j >> 13, c = (j >> 7) & 63, k = j & 127;
    float v = 0.f;
    if (c < NCLASS) v = (h ? W3r : W3l)[k * NCLASS + c];
    Wth3[j] = f2bf(v);
  }
}

// ------- mean aggregation, width 128, fp8 rows: 16 lanes/row, uint2/lane -------
// 4 edge-groups, 4 loads in flight (16 edges/iter); 8 acc; 2 shuffle rounds.
__global__ void k_aggq(const char* __restrict__ Xq, const int* __restrict__ off,
                       const int* __restrict__ col, int n, uint4* __restrict__ out) {
  int wid = (blockIdx.x * blockDim.x + threadIdx.x) >> 6;
  int lane = threadIdx.x & 63;
  if (wid >= n) return;
  int g = lane >> 4, q = lane & 15;
  unsigned qb = (unsigned)q << 3;  // 8 B per lane
  int s = off[wid], e = off[wid + 1];
  float acc[8];
#pragma unroll
  for (int t = 0; t < 8; ++t) acc[t] = 0.f;
  int e1 = e - 1;
  for (int j = s; j < e; j += 16) {
    int i0 = j + g, i1 = i0 + 4, i2 = i0 + 8, i3 = i0 + 12;
    int c0 = NTL(&col[min(i0, e1)]);
    int c1 = NTL(&col[min(i1, e1)]);
    int c2 = NTL(&col[min(i2, e1)]);
    int c3 = NTL(&col[min(i3, e1)]);
    float s0 = (i0 < e) ? 1.f : 0.f;
    float s1 = (i1 < e) ? 1.f : 0.f;
    float s2 = (i2 < e) ? 1.f : 0.f;
    float s3 = (i3 < e) ? 1.f : 0.f;
    uint2 u0 = *(const uint2*)(Xq + (((unsigned)c0 << 7) + qb));
    uint2 u1 = *(const uint2*)(Xq + (((unsigned)c1 << 7) + qb));
    uint2 u2 = *(const uint2*)(Xq + (((unsigned)c2 << 7) + qb));
    uint2 u3 = *(const uint2*)(Xq + (((unsigned)c3 << 7) + qb));
    ACCQ2(u0, s0);
    ACCQ2(u1, s1);
    ACCQ2(u2, s2);
    ACCQ2(u3, s3);
  }
#pragma unroll
  for (int t = 0; t < 8; ++t) {
    acc[t] += __shfl_xor(acc[t], 16);
    acc[t] += __shfl_xor(acc[t], 32);
  }
  float inv = 1.0f / fmaxf((float)(e - s), 1.0f);
  if (lane < 16) {
    uint4 o;
    o.x = (unsigned)f2bf(acc[0] * inv) | ((unsigned)f2bf(acc[1] * inv) << 16);
    o.y = (unsigned)f2bf(acc[2] * inv) | ((unsigned)f2bf(acc[3] * inv) << 16);
    o.z = (unsigned)f2bf(acc[4] * inv) | ((unsigned)f2bf(acc[5] * inv) << 16);
    o.w = (unsigned)f2bf(acc[6] * inv) | ((unsigned)f2bf(acc[7] * inv) << 16);
    out[(size_t)wid * 16 + q] = o;
  }
}

// ---------------- MFMA GEMM ----------------
// EPI 0: relu -> outB bf16 [n][128] AND (fp8*)outF [n][128]
// EPI 1: relu -> outB bf16 [n][128] AND outF f32 [n][128]
// EPI 3: cols 0..63 -> outB bf16 [n][64] (Y3); cols 64..127 -> (bf16*)outF [n][64] (R3)
template <int COLS, int HALVES, int EPI>
__global__ __launch_bounds__(256) void k_gemm_mfma(
    const unsigned short* __restrict__ Aagg, const unsigned short* __restrict__ Aroot,
    const unsigned short* __restrict__ Wth, const float* __restrict__ bias, int n,
    float* __restrict__ outF, unsigned short* __restrict__ outB) {
  constexpr int RF = 4;
  constexpr int CF = 4;
  __shared__ unsigned short aS[128 * 128];
  __shared__ unsigned short wS[COLS * 128];
  int tid = threadIdx.x;
  int w = tid >> 6, lane = tid & 63, l15 = lane & 15, kg = lane >> 4;
  int rowBase = blockIdx.x * 128;
  int r0 = (w >> 1) * 64;
  int c0 = (w & 1) * 64;

  f32x4 acc[RF][CF];
#pragma unroll
  for (int i = 0; i < RF; ++i)
#pragma unroll
    for (int j = 0; j < CF; ++j) acc[i][j] = (f32x4){0.f, 0.f, 0.f, 0.f};

#pragma unroll
  for (int half = 0; half < HALVES; ++half) {
    if (half) __syncthreads();
    {
      const unsigned short* As = half ? Aroot : Aagg;
#pragma unroll
      for (int it = 0; it < 8; ++it) {
        int row = it * 16 + (tid >> 4);
        int g = rowBase + row;
        g = (g < n) ? g : (n - 1);
        int cb = (tid & 15) << 4;
        int sb = cb ^ ((row & 7) << 4);
        const char* src = (const char*)(As + (size_t)g * 128) + sb;
        char* dst = (char*)aS + it * 4096 + (tid >> 6) * 1024;
        GLOAD_LDS16(src, dst);
      }
      const unsigned short* Ws = Wth + (size_t)half * COLS * 128;
#pragma unroll
      for (int it = 0; it < COLS / 16; ++it) {
        int c = it * 16 + (tid >> 4);
        int cb = (tid & 15) << 4;
        int sb = cb ^ ((c & 7) << 4);
        const char* src = (const char*)(Ws + (size_t)c * 128) + sb;
        char* dst = (char*)wS + it * 4096 + (tid >> 6) * 1024;
        GLOAD_LDS16(src, dst);
      }
      asm volatile("s_waitcnt vmcnt(0)" ::: "memory");
      __syncthreads();
    }
#pragma unroll
    for (int ks = 0; ks < 4; ++ks) {
      int kb = ks * 64 + kg * 16;
      bf16x8 av[RF], bv[CF];
#pragma unroll
      for (int i = 0; i < RF; ++i) {
        int row = r0 + i * 16 + l15;
        av[i] = *(const bf16x8*)((const char*)aS + row * 256 + (kb ^ ((row & 7) << 4)));
      }
#pragma unroll
      for (int j = 0; j < CF; ++j) {
        int c = c0 + j * 16 + l15;
        bv[j] = *(const bf16x8*)((const char*)wS + c * 256 + (kb ^ ((c & 7) << 4)));
      }
#pragma unroll
      for (int i = 0; i < RF; ++i)
#pragma unroll
        for (int j = 0; j < CF; ++j)
          acc[i][j] = __builtin_amdgcn_mfma_f32_16x16x32_bf16(av[i], bv[j], acc[i][j], 0, 0, 0);
    }
  }

  if (EPI == 3) {
    bool leftHalf = (c0 == 0);
    unsigned short* R3b = (unsigned short*)outF;
    float bcol[CF];
#pragma unroll
    for (int j = 0; j < CF; ++j) {
      int c = c0 + j * 16 + l15;
      bcol[j] = (!leftHalf && (c - 64) < NCLASS) ? bias[c - 64] : 0.f;
    }
#pragma unroll
    for (int i = 0; i < RF; ++i) {
#pragma unroll
      for (int r = 0; r < 4; ++r) {
        int row = rowBase + r0 + i * 16 + kg * 4 + r;
        if (row >= n) continue;
#pragma unroll
        for (int j = 0; j < CF; ++j) {
          int c = c0 + j * 16 + l15;
          if (leftHalf) {
            outB[(size_t)row * 64 + c] = f2bf(acc[i][j][r]);
          } else {
            R3b[(size_t)row * 64 + (c - 64)] = f2bf(acc[i][j][r] + bcol[j]);
          }
        }
      }
    }
  } else {
    float bcol[CF];
#pragma unroll
    for (int j = 0; j < CF; ++j) bcol[j] = bias[c0 + j * 16 + l15];
#pragma unroll
    for (int i = 0; i < RF; ++i) {
#pragma unroll
      for (int r = 0; r < 4; ++r) {
        int row = rowBase + r0 + i * 16 + kg * 4 + r;
        if (row >= n) continue;
#pragma unroll
        for (int j = 0; j < CF; ++j) {
          float v = fmaxf(acc[i][j][r] + bcol[j], 0.f);
          int c = c0 + j * 16 + l15;
          outB[(size_t)row * 128 + c] = f2bf(v);
          if (EPI == 1) outF[(size_t)row * 128 + c] = v;
          if (EPI == 0) {
            unsigned pk = __builtin_amdgcn_cvt_pk_fp8_f32(v, v, 0, false);
            ((unsigned char*)outF)[(size_t)row * 128 + c] = (unsigned char)(pk & 0xff);
          }
        }
      }
    }
  }
}

// ------- layer-3: width-64 bf16 mean agg + root + log_softmax, 8 lanes/row -------
// uint4 (8 bf16) per lane; 8 edge-groups; 16 edges/iter; native exp/log softmax.
__global__ void k_agg3ls(const char* __restrict__ Y3, const char* __restrict__ R3,
                         const int* __restrict__ off, const int* __restrict__ col, int n,
                         float* __restrict__ out) {
  int wid = (blockIdx.x * blockDim.x + threadIdx.x) >> 6;
  int lane = threadIdx.x & 63;
  if (wid >= n) return;
  int g = lane >> 3, q = lane & 7;
  unsigned qb = (unsigned)q << 4;
  int s = off[wid], e = off[wid + 1];
  float acc[8];
#pragma unroll
  for (int t = 0; t < 8; ++t) acc[t] = 0.f;
  int e1 = e - 1;
  for (int j = s; j < e; j += 16) {
    int i0 = j + g, i1 = i0 + 8;
    int c0 = NTL(&col[min(i0, e1)]);
    int c1 = NTL(&col[min(i1, e1)]);
    float s0 = (i0 < e) ? 1.f : 0.f;
    float s1 = (i1 < e) ? 1.f : 0.f;
    uint4 u0 = *(const uint4*)(Y3 + (((unsigned)c0 << 7) + qb));
    uint4 u1 = *(const uint4*)(Y3 + (((unsigned)c1 << 7) + qb));
    ACC8(u0, s0);
    ACC8(u1, s1);
  }
#pragma unroll
  for (int t = 0; t < 8; ++t) {
    acc[t] += __shfl_xor(acc[t], 8);
    acc[t] += __shfl_xor(acc[t], 16);
    acc[t] += __shfl_xor(acc[t], 32);
  }
  float inv = 1.0f / fmaxf((float)(e - s), 1.0f);
  uint4 ur = *(const uint4*)(R3 + (((unsigned)wid << 7) + qb));
  float v[8];
  v[0] = fmaf(acc[0], inv, bflo(ur.x));
  v[1] = fmaf(acc[1], inv, bfhi(ur.x));
  v[2] = fmaf(acc[2], inv, bflo(ur.y));
  v[3] = fmaf(acc[3], inv, bfhi(ur.y));
  v[4] = fmaf(acc[4], inv, bflo(ur.z));
  v[5] = fmaf(acc[5], inv, bfhi(ur.z));
  v[6] = fmaf(acc[6], inv, bflo(ur.w));
  v[7] = fmaf(acc[7], inv, bfhi(ur.w));
  bool valid = q < 5;  // cols q*8..q*8+7 < 40
  float m = -INFINITY;
  if (valid) {
#pragma unroll
    for (int t = 0; t < 8; ++t) m = fmaxf(m, v[t]);
  }
  m = fmaxf(m, __shfl_xor(m, 1));
  m = fmaxf(m, __shfl_xor(m, 2));
  m = fmaxf(m, __shfl_xor(m, 4));
  float sum = 0.f;
  if (valid) {
#pragma unroll
    for (int t = 0; t < 8; ++t) sum += __expf(v[t] - m);
  }
  sum += __shfl_xor(sum, 1);
  sum += __shfl_xor(sum, 2);
  sum += __shfl_xor(sum, 4);
  float ls = __logf(sum);
  if (lane < 5) {
    float4 o0 = make_float4(v[0] - m - ls, v[1] - m - ls, v[2] - m - ls, v[3] - m - ls);
    float4 o1 = make_float4(v[4] - m - ls, v[5] - m - ls, v[6] - m - ls, v[7] - m - ls);
    float* op = out + (size_t)wid * NCLASS + lane * 8;
    *(float4*)op = o0;
    *(float4*)(op + 4) = o1;
  }
}

extern "C" void kernel_launch(void* const* d_in, const int* in_sizes, int n_in,
                              void* d_out, int out_size, void* d_ws, size_t ws_size,
                              hipStream_t stream) {
  const float* x = (const float*)d_in[0];
  const int* ei = (const int*)d_in[1];
  const float* W1l = (const float*)d_in[2];
  const float* b1 = (const float*)d_in[3];
  const float* W1r = (const float*)d_in[4];
  const float* W2l = (const float*)d_in[5];
  const float* b2 = (const float*)d_in[6];
  const float* W2r = (const float*)d_in[7];
  const float* W3l = (const float*)d_in[8];
  const float* b3 = (const float*)d_in[9];
  const float* W3r = (const float*)d_in[10];

  int N = in_sizes[0] / 128;
  int E = in_sizes[1] / 2;
  const int* src = ei;
  const int* dst = ei + E;
  int NSB = (N + 511) >> 9;  // <= 256 for N <= 131072
  int nbB = (E + BEDG4 - 1) / BEDG4;

  char* wptr = (char*)d_ws;
  auto alloc = [&](size_t bytes) {
    void* p = (void*)wptr;
    wptr += (bytes + 255) & ~(size_t)255;
    return p;
  };
  int* off = (int*)alloc((size_t)(N + 1) * 4);
  int* col = (int*)alloc((size_t)E * 4);
  int* bcnt = (int*)alloc((size_t)nbB * 256 * 4);
  int* tot = (int*)alloc(256 * 4);
  int* base2 = (int*)alloc(257 * 4);
  unsigned short* Wth1 = (unsigned short*)alloc(32768 * 2);
  unsigned short* Wth2 = (unsigned short*)alloc(32768 * 2);
  unsigned short* Wth3 = (unsigned short*)alloc(16384 * 2);
  unsigned short* xb = (unsigned short*)alloc((size_t)N * 128 * 2);
  unsigned short* mb = (unsigned short*)alloc((size_t)N * 128 * 2);
  unsigned short* h1 = (unsigned short*)alloc((size_t)N * 128 * 2);
  unsigned short* h2 = (unsigned short*)alloc((size_t)N * 128 * 2);
  unsigned char* xq = (unsigned char*)alloc((size_t)N * 128);
  unsigned char* h1q = (unsigned char*)alloc((size_t)N * 128);

  float* outLS = (float*)d_out;                     // [N][40]
  float* emb = (float*)d_out + (size_t)N * NCLASS;  // [N][128]

  // Aliases (lifetimes disjoint on the stream):
  int* ebuf2 = (int*)h2;     // E ints; dead before gemm2 writes h2
  unsigned short* Y3 = mb;   // bf16 [N][64]; mb dead after gemm2
  unsigned short* R3b = h1;  // bf16 [N][64]; h1 dead after gemm2

  // CSR build: single-level counting sort by 512-node range, no global atomics
  k_bcountF<<<nbB, 256, 0, stream>>>(dst, E, bcnt);
  k_bscanF<<<NSB, 256, 0, stream>>>(bcnt, nbB, tot);
  k_baseF<<<1, 256, 0, stream>>>(tot, NSB, N, E, base2, off);
  k_placeF<<<nbB, 256, 0, stream>>>(dst, src, E, bcnt, base2, ebuf2);
  k_csrF<<<NSB, 256, 0, stream>>>(ebuf2, base2, tot, N, off, col);

  int n8 = N * 16;
  k_cast<<<(n8 + 255) / 256, 256, 0, stream>>>((const float4*)x, (uint4*)xb, (uint2*)xq,
                                               n8);
  k_prepw<<<(81920 + 255) / 256, 256, 0, stream>>>(W1l, W1r, W2l, W2r, W3l, W3r, Wth1,
                                                   Wth2, Wth3);

  int ab = (N * 64 + 255) / 256;
  int gb = (N + 127) / 128;

  // layer 1: fp8 gather of xq -> mb; gemm writes h1 bf16 + h1q fp8
  k_aggq<<<ab, 256, 0, stream>>>((const char*)xq, off, col, N, (uint4*)mb);
  k_gemm_mfma<128, 2, 0><<<gb, 256, 0, stream>>>(mb, xb, Wth1, b1, N, (float*)h1q, h1);
  // layer 2: fp8 gather of h1q -> mb; gemm writes emb f32 + h2 bf16
  k_aggq<<<ab, 256, 0, stream>>>((const char*)h1q, off, col, N, (uint4*)mb);
  k_gemm_mfma<128, 2, 1><<<gb, 256, 0, stream>>>(mb, h1, Wth2, b2, N, emb, h2);
  // layer 3: project first (Y3 = h2@W3l bf16, R3 = h2@W3r + b3 bf16), then
  // width-64 bf16 gather + fused root add + log_softmax
  k_gemm_mfma<128, 1, 3><<<gb, 256, 0, stream>>>(h2, nullptr, Wth3, b3, N, (float*)R3b, Y3);
  k_agg3ls<<<ab, 256, 0, stream>>>((const char*)Y3, (const char*)R3b, off, col, N, outLS);
}

// Round 13
// 277.014 us; speedup vs baseline: 1.0956x; 1.0051x over previous
//
#include <hip/hip_runtime.h>
#include <math.h>

#define NCLASS 40
#define BEDG4 4096  // edges per chunk block in CSR build
#define CAP 24576   // LDS col-staging capacity per 512-node sub-bucket

typedef float f32x4 __attribute__((ext_vector_type(4)));
typedef float f32x2 __attribute__((ext_vector_type(2)));
typedef __bf16 bf16x8 __attribute__((ext_vector_type(8)));

typedef __attribute__((address_space(1))) const void gv_t;
typedef __attribute__((address_space(3))) void lv_t;
#define GLOAD_LDS16(g, l) __builtin_amdgcn_global_load_lds((gv_t*)(g), (lv_t*)(l), 16, 0, 0)
#define NTL(p) __builtin_nontemporal_load(p)

__device__ inline unsigned short f2bf(float f) {
  unsigned u = __float_as_uint(f);
  unsigned r = (u + 0x7fff + ((u >> 16) & 1)) >> 16;
  return (unsigned short)r;
}
__device__ inline float bflo(unsigned v) { return __uint_as_float(v << 16); }
__device__ inline float bfhi(unsigned v) { return __uint_as_float(v & 0xffff0000u); }

// decode 8 fp8 (one uint2) and accumulate with scale
#define ACCQ2(u, sc)                                                  \
  do {                                                                \
    f32x2 p_;                                                         \
    p_ = __builtin_amdgcn_cvt_pk_f32_fp8(u.x, false);                 \
    acc[0] = fmaf(p_.x, sc, acc[0]); acc[1] = fmaf(p_.y, sc, acc[1]); \
    p_ = __builtin_amdgcn_cvt_pk_f32_fp8(u.x, true);                  \
    acc[2] = fmaf(p_.x, sc, acc[2]); acc[3] = fmaf(p_.y, sc, acc[3]); \
    p_ = __builtin_amdgcn_cvt_pk_f32_fp8(u.y, false);                 \
    acc[4] = fmaf(p_.x, sc, acc[4]); acc[5] = fmaf(p_.y, sc, acc[5]); \
    p_ = __builtin_amdgcn_cvt_pk_f32_fp8(u.y, true);                  \
    acc[6] = fmaf(p_.x, sc, acc[6]); acc[7] = fmaf(p_.y, sc, acc[7]); \
  } while (0)

// ============ CSR build: single-level counting sort by 512-node range =========
__global__ __launch_bounds__(256) void k_bcountF(const int* __restrict__ dst, int E,
                                                 int* __restrict__ bcnt) {
  __shared__ int lc[256];
  int k = blockIdx.x;
  int tid = threadIdx.x;
  lc[tid] = 0;
  __syncthreads();
  int lo = k * BEDG4, hi = min(lo + BEDG4, E);
  for (int i = lo + tid; i < hi; i += 256) atomicAdd(&lc[NTL(&dst[i]) >> 9], 1);
  __syncthreads();
  bcnt[k * 256 + tid] = lc[tid];
}

__global__ __launch_bounds__(256) void k_bscanF(int* __restrict__ bcnt, int nbB,
                                                int* __restrict__ tot) {
  __shared__ int tmp[256];
  __shared__ int carryS;
  int b = blockIdx.x;
  int tid = threadIdx.x;
  if (tid == 0) carryS = 0;
  __syncthreads();
  for (int c0 = 0; c0 < nbB; c0 += 256) {
    int idx = c0 + tid;
    int v = (idx < nbB) ? bcnt[idx * 256 + b] : 0;
    tmp[tid] = v;
    __syncthreads();
    for (int d = 1; d < 256; d <<= 1) {
      int t = (tid >= d) ? tmp[tid - d] : 0;
      __syncthreads();
      tmp[tid] += t;
      __syncthreads();
    }
    if (idx < nbB) bcnt[idx * 256 + b] = carryS + tmp[tid] - v;
    __syncthreads();
    if (tid == 255) carryS += tmp[255];
    __syncthreads();
  }
  if (tid == 0) tot[b] = carryS;
}

__global__ __launch_bounds__(256) void k_baseF(const int* __restrict__ tot, int NSB,
                                               int N, int E, int* __restrict__ base2,
                                               int* __restrict__ off) {
  __shared__ int tmp[256];
  int tid = threadIdx.x;
  int v = (tid < NSB) ? tot[tid] : 0;
  tmp[tid] = v;
  __syncthreads();
  for (int d = 1; d < 256; d <<= 1) {
    int t = (tid >= d) ? tmp[tid - d] : 0;
    __syncthreads();
    tmp[tid] += t;
    __syncthreads();
  }
  base2[tid] = tmp[tid] - v;
  if (tid == 0) {
    base2[NSB] = E;
    off[N] = E;
  }
}

__global__ __launch_bounds__(256) void k_placeF(const int* __restrict__ dst,
                                                const int* __restrict__ src, int E,
                                                const int* __restrict__ bcnt,
                                                const int* __restrict__ base2,
                                                int* __restrict__ ebuf2) {
  __shared__ int lb[256];
  int k = blockIdx.x;
  int tid = threadIdx.x;
  lb[tid] = base2[tid] + bcnt[k * 256 + tid];
  __syncthreads();
  int lo = k * BEDG4, hi = min(lo + BEDG4, E);
  for (int i = lo + tid; i < hi; i += 256) {
    int d = NTL(&dst[i]);
    int s = NTL(&src[i]);
    int pos = atomicAdd(&lb[d >> 9], 1);
    ebuf2[pos] = (int)(((unsigned)(d & 511) << 17) | (unsigned)s);
  }
}

__global__ __launch_bounds__(256) void k_csrF(const int* __restrict__ ebuf2,
                                              const int* __restrict__ base2,
                                              const int* __restrict__ tot, int N,
                                              int* __restrict__ off,
                                              int* __restrict__ col) {
  __shared__ int cnt[512];
  __shared__ int cur[512];
  __shared__ int tmp[256];
  __shared__ int stage[CAP];
  int sb = blockIdx.x;
  int tid = threadIdx.x;
  int node0 = sb << 9;
  if (node0 >= N) return;
  int nn = min(512, N - node0);
  int lo = base2[sb];
  int t2 = tot[sb];

  cnt[tid] = 0;
  cnt[tid + 256] = 0;
  __syncthreads();
  for (int i = lo + tid; i < lo + t2; i += 256)
    atomicAdd(&cnt[(((unsigned)ebuf2[i]) >> 17) & 511], 1);
  __syncthreads();

  int v0 = cnt[2 * tid], v1 = cnt[2 * tid + 1];
  int s = v0 + v1;
  tmp[tid] = s;
  __syncthreads();
  for (int d = 1; d < 256; d <<= 1) {
    int t = (tid >= d) ? tmp[tid - d] : 0;
    __syncthreads();
    tmp[tid] += t;
    __syncthreads();
  }
  int excl = tmp[tid] - s;
  cnt[2 * tid] = excl;
  cnt[2 * tid + 1] = excl + v0;
  cur[2 * tid] = excl;
  cur[2 * tid + 1] = excl + v0;
  __syncthreads();

  for (int i = tid; i < nn; i += 256) off[node0 + i] = lo + cnt[i];

  if (t2 <= CAP) {
    for (int i = lo + tid; i < lo + t2; i += 256) {
      unsigned pk = (unsigned)ebuf2[i];
      int pos = atomicAdd(&cur[(pk >> 17) & 511], 1);
      stage[pos] = (int)(pk & 0x1FFFFu);
    }
    __syncthreads();
    for (int i = tid; i < t2; i += 256) col[lo + i] = stage[i];
  } else {
    for (int i = lo + tid; i < lo + t2; i += 256) {
      unsigned pk = (unsigned)ebuf2[i];
      int pos = atomicAdd(&cur[(pk >> 17) & 511], 1);
      col[lo + pos] = (int)(pk & 0x1FFFFu);
    }
  }
}

// ---------------- casts / weight prep ----------------
__global__ void k_cast(const float4* __restrict__ x, uint4* __restrict__ xb,
                       uint2* __restrict__ xq, int n8) {
  int i = blockIdx.x * blockDim.x + threadIdx.x;
  if (i >= n8) return;
  float4 a = x[i * 2], b = x[i * 2 + 1];
  uint4 o;
  o.x = (unsigned)f2bf(a.x) | ((unsigned)f2bf(a.y) << 16);
  o.y = (unsigned)f2bf(a.z) | ((unsigned)f2bf(a.w) << 16);
  o.z = (unsigned)f2bf(b.x) | ((unsigned)f2bf(b.y) << 16);
  o.w = (unsigned)f2bf(b.z) | ((unsigned)f2bf(b.w) << 16);
  xb[i] = o;
  unsigned lo = __builtin_amdgcn_cvt_pk_fp8_f32(a.x, a.y, 0, false);
  lo = __builtin_amdgcn_cvt_pk_fp8_f32(a.z, a.w, lo, true);
  unsigned hi = __builtin_amdgcn_cvt_pk_fp8_f32(b.x, b.y, 0, false);
  hi = __builtin_amdgcn_cvt_pk_fp8_f32(b.z, b.w, hi, true);
  xq[i] = make_uint2(lo, hi);
}

// Wth layout: [half][COLS][128] bf16. half0=Wl^T, half1=Wr^T.
__global__ void k_prepw(const float* __restrict__ W1l, const float* __restrict__ W1r,
                        const float* __restrict__ W2l, const float* __restrict__ W2r,
                        const float* __restrict__ W3l, const float* __restrict__ W3r,
                        unsigned short* __restrict__ Wth1, unsigned short* __restrict__ Wth2,
                        unsigned short* __restrict__ Wth3) {
  int idx = blockIdx.x * blockDim.x + threadIdx.x;
  if (idx < 32768) {
    int h = idx >> 14, c = (idx >> 7) & 127, k = idx & 127;
    const float* W = h ? W1r : W1l;
    Wth1[idx] = f2bf(W[k * 128 + c]);
  } else if (idx < 65536) {
    int j = idx - 32768;
    int h = j >> 14, c = (j >> 7) & 127, k = j & 127;
    const float* W = h ? W2r : W2l;
    Wth2[j] = f2bf(W[k * 128 + c]);
  } else if (idx < 65536 + 16384) {
    int j = idx - 65536;
    int h = j >> 13, c = (j >> 7) & 63, k = j & 127;
    float v = 0.f;
    if (c < NCLASS) v = (h ? W3r : W3l)[k * NCLASS + c];
    Wth3[j] = f2bf(v);
  }
}

// ------- mean aggregation, width 128, fp8 rows: 16 lanes/row, uint2/lane -------
// 4 edge-groups, 4 loads in flight (16 edges/iter); 8 acc; 2 shuffle rounds.
__global__ void k_aggq(const char* __restrict__ Xq, const int* __restrict__ off,
                       const int* __restrict__ col, int n, uint4* __restrict__ out) {
  int wid = (blockIdx.x * blockDim.x + threadIdx.x) >> 6;
  int lane = threadIdx.x & 63;
  if (wid >= n) return;
  int g = lane >> 4, q = lane & 15;
  unsigned qb = (unsigned)q << 3;  // 8 B per lane
  int s = off[wid], e = off[wid + 1];
  float acc[8];
#pragma unroll
  for (int t = 0; t < 8; ++t) acc[t] = 0.f;
  int e1 = e - 1;
  for (int j = s; j < e; j += 16) {
    int i0 = j + g, i1 = i0 + 4, i2 = i0 + 8, i3 = i0 + 12;
    int c0 = NTL(&col[min(i0, e1)]);
    int c1 = NTL(&col[min(i1, e1)]);
    int c2 = NTL(&col[min(i2, e1)]);
    int c3 = NTL(&col[min(i3, e1)]);
    float s0 = (i0 < e) ? 1.f : 0.f;
    float s1 = (i1 < e) ? 1.f : 0.f;
    float s2 = (i2 < e) ? 1.f : 0.f;
    float s3 = (i3 < e) ? 1.f : 0.f;
    uint2 u0 = *(const uint2*)(Xq + (((unsigned)c0 << 7) + qb));
    uint2 u1 = *(const uint2*)(Xq + (((unsigned)c1 << 7) + qb));
    uint2 u2 = *(const uint2*)(Xq + (((unsigned)c2 << 7) + qb));
    uint2 u3 = *(const uint2*)(Xq + (((unsigned)c3 << 7) + qb));
    ACCQ2(u0, s0);
    ACCQ2(u1, s1);
    ACCQ2(u2, s2);
    ACCQ2(u3, s3);
  }
#pragma unroll
  for (int t = 0; t < 8; ++t) {
    acc[t] += __shfl_xor(acc[t], 16);
    acc[t] += __shfl_xor(acc[t], 32);
  }
  float inv = 1.0f / fmaxf((float)(e - s), 1.0f);
  if (lane < 16) {
    uint4 o;
    o.x = (unsigned)f2bf(acc[0] * inv) | ((unsigned)f2bf(acc[1] * inv) << 16);
    o.y = (unsigned)f2bf(acc[2] * inv) | ((unsigned)f2bf(acc[3] * inv) << 16);
    o.z = (unsigned)f2bf(acc[4] * inv) | ((unsigned)f2bf(acc[5] * inv) << 16);
    o.w = (unsigned)f2bf(acc[6] * inv) | ((unsigned)f2bf(acc[7] * inv) << 16);
    out[(size_t)wid * 16 + q] = o;
  }
}

// ---------------- MFMA GEMM ----------------
// EPI 0: relu -> outB bf16 [n][128] AND (fp8*)outF [n][128]
// EPI 1: relu -> outB bf16 [n][128] AND outF f32 [n][128]
// EPI 3: cols 0..63 -> (fp8*)outB [n][64] (Y3q); cols 64..127 -> (bf16*)outF [n][64] (R3)
template <int COLS, int HALVES, int EPI>
__global__ __launch_bounds__(256) void k_gemm_mfma(
    const unsigned short* __restrict__ Aagg, const unsigned short* __restrict__ Aroot,
    const unsigned short* __restrict__ Wth, const float* __restrict__ bias, int n,
    float* __restrict__ outF, unsigned short* __restrict__ outB) {
  constexpr int RF = 4;
  constexpr int CF = 4;
  __shared__ unsigned short aS[128 * 128];
  __shared__ unsigned short wS[COLS * 128];
  int tid = threadIdx.x;
  int w = tid >> 6, lane = tid & 63, l15 = lane & 15, kg = lane >> 4;
  int rowBase = blockIdx.x * 128;
  int r0 = (w >> 1) * 64;
  int c0 = (w & 1) * 64;

  f32x4 acc[RF][CF];
#pragma unroll
  for (int i = 0; i < RF; ++i)
#pragma unroll
    for (int j = 0; j < CF; ++j) acc[i][j] = (f32x4){0.f, 0.f, 0.f, 0.f};

#pragma unroll
  for (int half = 0; half < HALVES; ++half) {
    if (half) __syncthreads();
    {
      const unsigned short* As = half ? Aroot : Aagg;
#pragma unroll
      for (int it = 0; it < 8; ++it) {
        int row = it * 16 + (tid >> 4);
        int g = rowBase + row;
        g = (g < n) ? g : (n - 1);
        int cb = (tid & 15) << 4;
        int sb = cb ^ ((row & 7) << 4);
        const char* src = (const char*)(As + (size_t)g * 128) + sb;
        char* dst = (char*)aS + it * 4096 + (tid >> 6) * 1024;
        GLOAD_LDS16(src, dst);
      }
      const unsigned short* Ws = Wth + (size_t)half * COLS * 128;
#pragma unroll
      for (int it = 0; it < COLS / 16; ++it) {
        int c = it * 16 + (tid >> 4);
        int cb = (tid & 15) << 4;
        int sb = cb ^ ((c & 7) << 4);
        const char* src = (const char*)(Ws + (size_t)c * 128) + sb;
        char* dst = (char*)wS + it * 4096 + (tid >> 6) * 1024;
        GLOAD_LDS16(src, dst);
      }
      asm volatile("s_waitcnt vmcnt(0)" ::: "memory");
      __syncthreads();
    }
#pragma unroll
    for (int ks = 0; ks < 4; ++ks) {
      int kb = ks * 64 + kg * 16;
      bf16x8 av[RF], bv[CF];
#pragma unroll
      for (int i = 0; i < RF; ++i) {
        int row = r0 + i * 16 + l15;
        av[i] = *(const bf16x8*)((const char*)aS + row * 256 + (kb ^ ((row & 7) << 4)));
      }
#pragma unroll
      for (int j = 0; j < CF; ++j) {
        int c = c0 + j * 16 + l15;
        bv[j] = *(const bf16x8*)((const char*)wS + c * 256 + (kb ^ ((c & 7) << 4)));
      }
#pragma unroll
      for (int i = 0; i < RF; ++i)
#pragma unroll
        for (int j = 0; j < CF; ++j)
          acc[i][j] = __builtin_amdgcn_mfma_f32_16x16x32_bf16(av[i], bv[j], acc[i][j], 0, 0, 0);
    }
  }

  if (EPI == 3) {
    bool leftHalf = (c0 == 0);
    unsigned char* Y3q = (unsigned char*)outB;
    unsigned short* R3b = (unsigned short*)outF;
    float bcol[CF];
#pragma unroll
    for (int j = 0; j < CF; ++j) {
      int c = c0 + j * 16 + l15;
      bcol[j] = (!leftHalf && (c - 64) < NCLASS) ? bias[c - 64] : 0.f;
    }
#pragma unroll
    for (int i = 0; i < RF; ++i) {
#pragma unroll
      for (int r = 0; r < 4; ++r) {
        int row = rowBase + r0 + i * 16 + kg * 4 + r;
        if (row >= n) continue;
#pragma unroll
        for (int j = 0; j < CF; ++j) {
          int c = c0 + j * 16 + l15;
          if (leftHalf) {
            unsigned pk = __builtin_amdgcn_cvt_pk_fp8_f32(acc[i][j][r], acc[i][j][r], 0, false);
            Y3q[(size_t)row * 64 + c] = (unsigned char)(pk & 0xff);
          } else {
            R3b[(size_t)row * 64 + (c - 64)] = f2bf(acc[i][j][r] + bcol[j]);
          }
        }
      }
    }
  } else {
    float bcol[CF];
#pragma unroll
    for (int j = 0; j < CF; ++j) bcol[j] = bias[c0 + j * 16 + l15];
#pragma unroll
    for (int i = 0; i < RF; ++i) {
#pragma unroll
      for (int r = 0; r < 4; ++r) {
        int row = rowBase + r0 + i * 16 + kg * 4 + r;
        if (row >= n) continue;
#pragma unroll
        for (int j = 0; j < CF; ++j) {
          float v = fmaxf(acc[i][j][r] + bcol[j], 0.f);
          int c = c0 + j * 16 + l15;
          outB[(size_t)row * 128 + c] = f2bf(v);
          if (EPI == 1) outF[(size_t)row * 128 + c] = v;
          if (EPI == 0) {
            unsigned pk = __builtin_amdgcn_cvt_pk_fp8_f32(v, v, 0, false);
            ((unsigned char*)outF)[(size_t)row * 128 + c] = (unsigned char)(pk & 0xff);
          }
        }
      }
    }
  }
}

// ------- layer-3: width-64 fp8 mean agg + bf16 root + log_softmax, 8 lanes/row -------
// Y3q fp8 [n][64] (cols>=40 zero): uint2 (8 fp8) per lane; 8 edge-groups;
// 16 edges/iter; 8 acc; 3 reduce rounds; native exp/log softmax.
__global__ void k_agg3ls(const char* __restrict__ Y3q, const char* __restrict__ R3,
                         const int* __restrict__ off, const int* __restrict__ col, int n,
                         float* __restrict__ out) {
  int wid = (blockIdx.x * blockDim.x + threadIdx.x) >> 6;
  int lane = threadIdx.x & 63;
  if (wid >= n) return;
  int g = lane >> 3, q = lane & 7;
  unsigned qb = (unsigned)q << 3;  // 8 fp8 bytes per lane within a 64-B row
  int s = off[wid], e = off[wid + 1];
  float acc[8];
#pragma unroll
  for (int t = 0; t < 8; ++t) acc[t] = 0.f;
  int e1 = e - 1;
  for (int j = s; j < e; j += 16) {
    int i0 = j + g, i1 = i0 + 8;
    int c0 = NTL(&col[min(i0, e1)]);
    int c1 = NTL(&col[min(i1, e1)]);
    float s0 = (i0 < e) ? 1.f : 0.f;
    float s1 = (i1 < e) ? 1.f : 0.f;
    uint2 u0 = *(const uint2*)(Y3q + (((unsigned)c0 << 6) + qb));
    uint2 u1 = *(const uint2*)(Y3q + (((unsigned)c1 << 6) + qb));
    ACCQ2(u0, s0);
    ACCQ2(u1, s1);
  }
#pragma unroll
  for (int t = 0; t < 8; ++t) {
    acc[t] += __shfl_xor(acc[t], 8);
    acc[t] += __shfl_xor(acc[t], 16);
    acc[t] += __shfl_xor(acc[t], 32);
  }
  float inv = 1.0f / fmaxf((float)(e - s), 1.0f);
  uint4 ur = *(const uint4*)(R3 + (((unsigned)wid << 7) + ((unsigned)q << 4)));
  float v[8];
  v[0] = fmaf(acc[0], inv, bflo(ur.x));
  v[1] = fmaf(acc[1], inv, bfhi(ur.x));
  v[2] = fmaf(acc[2], inv, bflo(ur.y));
  v[3] = fmaf(acc[3], inv, bfhi(ur.y));
  v[4] = fmaf(acc[4], inv, bflo(ur.z));
  v[5] = fmaf(acc[5], inv, bfhi(ur.z));
  v[6] = fmaf(acc[6], inv, bflo(ur.w));
  v[7] = fmaf(acc[7], inv, bfhi(ur.w));
  bool valid = q < 5;  // cols q*8..q*8+7 < 40
  float m = -INFINITY;
  if (valid) {
#pragma unroll
    for (int t = 0; t < 8; ++t) m = fmaxf(m, v[t]);
  }
  m = fmaxf(m, __shfl_xor(m, 1));
  m = fmaxf(m, __shfl_xor(m, 2));
  m = fmaxf(m, __shfl_xor(m, 4));
  float sum = 0.f;
  if (valid) {
#pragma unroll
    for (int t = 0; t < 8; ++t) sum += __expf(v[t] - m);
  }
  sum += __shfl_xor(sum, 1);
  sum += __shfl_xor(sum, 2);
  sum += __shfl_xor(sum, 4);
  float ls = __logf(sum);
  if (lane < 5) {
    float4 o0 = make_float4(v[0] - m - ls, v[1] - m - ls, v[2] - m - ls, v[3] - m - ls);
    float4 o1 = make_float4(v[4] - m - ls, v[5] - m - ls, v[6] - m - ls, v[7] - m - ls);
    float* op = out + (size_t)wid * NCLASS + lane * 8;
    *(float4*)op = o0;
    *(float4*)(op + 4) = o1;
  }
}

extern "C" void kernel_launch(void* const* d_in, const int* in_sizes, int n_in,
                              void* d_out, int out_size, void* d_ws, size_t ws_size,
                              hipStream_t stream) {
  const float* x = (const float*)d_in[0];
  const int* ei = (const int*)d_in[1];
  const float* W1l = (const float*)d_in[2];
  const float* b1 = (const float*)d_in[3];
  const float* W1r = (const float*)d_in[4];
  const float* W2l = (const float*)d_in[5];
  const float* b2 = (const float*)d_in[6];
  const float* W2r = (const float*)d_in[7];
  const float* W3l = (const float*)d_in[8];
  const float* b3 = (const float*)d_in[9];
  const float* W3r = (const float*)d_in[10];

  int N = in_sizes[0] / 128;
  int E = in_sizes[1] / 2;
  const int* src = ei;
  const int* dst = ei + E;
  int NSB = (N + 511) >> 9;  // <= 256 for N <= 131072
  int nbB = (E + BEDG4 - 1) / BEDG4;

  char* wptr = (char*)d_ws;
  auto alloc = [&](size_t bytes) {
    void* p = (void*)wptr;
    wptr += (bytes + 255) & ~(size_t)255;
    return p;
  };
  int* off = (int*)alloc((size_t)(N + 1) * 4);
  int* col = (int*)alloc((size_t)E * 4);
  int* bcnt = (int*)alloc((size_t)nbB * 256 * 4);
  int* tot = (int*)alloc(256 * 4);
  int* base2 = (int*)alloc(257 * 4);
  unsigned short* Wth1 = (unsigned short*)alloc(32768 * 2);
  unsigned short* Wth2 = (unsigned short*)alloc(32768 * 2);
  unsigned short* Wth3 = (unsigned short*)alloc(16384 * 2);
  unsigned short* xb = (unsigned short*)alloc((size_t)N * 128 * 2);
  unsigned short* mb = (unsigned short*)alloc((size_t)N * 128 * 2);
  unsigned short* h1 = (unsigned short*)alloc((size_t)N * 128 * 2);
  unsigned short* h2 = (unsigned short*)alloc((size_t)N * 128 * 2);
  unsigned char* xq = (unsigned char*)alloc((size_t)N * 128);
  unsigned char* h1q = (unsigned char*)alloc((size_t)N * 128);

  float* outLS = (float*)d_out;                     // [N][40]
  float* emb = (float*)d_out + (size_t)N * NCLASS;  // [N][128]

  // Aliases (lifetimes disjoint on the stream):
  int* ebuf2 = (int*)h2;                    // E ints; dead before gemm2 writes h2
  unsigned char* Y3q = (unsigned char*)mb;  // fp8 [N][64]; mb dead after gemm2
  unsigned short* R3b = h1;                 // bf16 [N][64]; h1 dead after gemm2

  // CSR build: single-level counting sort by 512-node range, no global atomics
  k_bcountF<<<nbB, 256, 0, stream>>>(dst, E, bcnt);
  k_bscanF<<<NSB, 256, 0, stream>>>(bcnt, nbB, tot);
  k_baseF<<<1, 256, 0, stream>>>(tot, NSB, N, E, base2, off);
  k_placeF<<<nbB, 256, 0, stream>>>(dst, src, E, bcnt, base2, ebuf2);
  k_csrF<<<NSB, 256, 0, stream>>>(ebuf2, base2, tot, N, off, col);

  int n8 = N * 16;
  k_cast<<<(n8 + 255) / 256, 256, 0, stream>>>((const float4*)x, (uint4*)xb, (uint2*)xq,
                                               n8);
  k_prepw<<<(81920 + 255) / 256, 256, 0, stream>>>(W1l, W1r, W2l, W2r, W3l, W3r, Wth1,
                                                   Wth2, Wth3);

  int ab = (N * 64 + 255) / 256;
  int gb = (N + 127) / 128;

  // layer 1: fp8 gather of xq -> mb; gemm writes h1 bf16 + h1q fp8
  k_aggq<<<ab, 256, 0, stream>>>((const char*)xq, off, col, N, (uint4*)mb);
  k_gemm_mfma<128, 2, 0><<<gb, 256, 0, stream>>>(mb, xb, Wth1, b1, N, (float*)h1q, h1);
  // layer 2: fp8 gather of h1q -> mb; gemm writes emb f32 + h2 bf16
  k_aggq<<<ab, 256, 0, stream>>>((const char*)h1q, off, col, N, (uint4*)mb);
  k_gemm_mfma<128, 2, 1><<<gb, 256, 0, stream>>>(mb, h1, Wth2, b2, N, emb, h2);
  // layer 3: project first (Y3q = fp8(h2@W3l), R3 = bf16(h2@W3r + b3)), then
  // width-64 fp8 gather + fused root add + log_softmax
  k_gemm_mfma<128, 1, 3><<<gb, 256, 0, stream>>>(h2, nullptr, Wth3, b3, N, (float*)R3b,
                                                 (unsigned short*)Y3q);
  k_agg3ls<<<ab, 256, 0, stream>>>((const char*)Y3q, (const char*)R3b, off, col, N, outLS);
}

// Round 14
// 275.165 us; speedup vs baseline: 1.1030x; 1.0067x over previous
//
#include <hip/hip_runtime.h>
#include <math.h>

#define NCLASS 40
#define BEDG4 4096  // edges per chunk block in CSR build
#define CAP 24576   // LDS col-staging capacity per 512-node sub-bucket

typedef float f32x4 __attribute__((ext_vector_type(4)));
typedef float f32x2 __attribute__((ext_vector_type(2)));
typedef __bf16 bf16x8 __attribute__((ext_vector_type(8)));

typedef __attribute__((address_space(1))) const void gv_t;
typedef __attribute__((address_space(3))) void lv_t;
#define GLOAD_LDS16(g, l) __builtin_amdgcn_global_load_lds((gv_t*)(g), (lv_t*)(l), 16, 0, 0)
#define NTL(p) __builtin_nontemporal_load(p)

__device__ inline unsigned short f2bf(float f) {
  unsigned u = __float_as_uint(f);
  unsigned r = (u + 0x7fff + ((u >> 16) & 1)) >> 16;
  return (unsigned short)r;
}
__device__ inline float bflo(unsigned v) { return __uint_as_float(v << 16); }
__device__ inline float bfhi(unsigned v) { return __uint_as_float(v & 0xffff0000u); }

// decode 8 fp8 (one uint2), accumulate with scale (masked tail path)
#define ACCQ2(u, sc)                                                  \
  do {                                                                \
    f32x2 p_;                                                         \
    p_ = __builtin_amdgcn_cvt_pk_f32_fp8(u.x, false);                 \
    acc[0] = fmaf(p_.x, sc, acc[0]); acc[1] = fmaf(p_.y, sc, acc[1]); \
    p_ = __builtin_amdgcn_cvt_pk_f32_fp8(u.x, true);                  \
    acc[2] = fmaf(p_.x, sc, acc[2]); acc[3] = fmaf(p_.y, sc, acc[3]); \
    p_ = __builtin_amdgcn_cvt_pk_f32_fp8(u.y, false);                 \
    acc[4] = fmaf(p_.x, sc, acc[4]); acc[5] = fmaf(p_.y, sc, acc[5]); \
    p_ = __builtin_amdgcn_cvt_pk_f32_fp8(u.y, true);                  \
    acc[6] = fmaf(p_.x, sc, acc[6]); acc[7] = fmaf(p_.y, sc, acc[7]); \
  } while (0)

// decode 8 fp8 (one uint2), accumulate unmasked (full-iteration path)
#define ACCQ2U(u)                                     \
  do {                                                \
    f32x2 p_;                                         \
    p_ = __builtin_amdgcn_cvt_pk_f32_fp8(u.x, false); \
    acc[0] += p_.x; acc[1] += p_.y;                   \
    p_ = __builtin_amdgcn_cvt_pk_f32_fp8(u.x, true);  \
    acc[2] += p_.x; acc[3] += p_.y;                   \
    p_ = __builtin_amdgcn_cvt_pk_f32_fp8(u.y, false); \
    acc[4] += p_.x; acc[5] += p_.y;                   \
    p_ = __builtin_amdgcn_cvt_pk_f32_fp8(u.y, true);  \
    acc[6] += p_.x; acc[7] += p_.y;                   \
  } while (0)

// ============ CSR build: single-level counting sort by 512-node range =========
__global__ __launch_bounds__(256) void k_bcountF(const int* __restrict__ dst, int E,
                                                 int* __restrict__ bcnt) {
  __shared__ int lc[256];
  int k = blockIdx.x;
  int tid = threadIdx.x;
  lc[tid] = 0;
  __syncthreads();
  int lo = k * BEDG4, hi = min(lo + BEDG4, E);
  for (int i = lo + tid; i < hi; i += 256) atomicAdd(&lc[NTL(&dst[i]) >> 9], 1);
  __syncthreads();
  bcnt[k * 256 + tid] = lc[tid];
}

__global__ __launch_bounds__(256) void k_bscanF(int* __restrict__ bcnt, int nbB,
                                                int* __restrict__ tot) {
  __shared__ int tmp[256];
  __shared__ int carryS;
  int b = blockIdx.x;
  int tid = threadIdx.x;
  if (tid == 0) carryS = 0;
  __syncthreads();
  for (int c0 = 0; c0 < nbB; c0 += 256) {
    int idx = c0 + tid;
    int v = (idx < nbB) ? bcnt[idx * 256 + b] : 0;
    tmp[tid] = v;
    __syncthreads();
    for (int d = 1; d < 256; d <<= 1) {
      int t = (tid >= d) ? tmp[tid - d] : 0;
      __syncthreads();
      tmp[tid] += t;
      __syncthreads();
    }
    if (idx < nbB) bcnt[idx * 256 + b] = carryS + tmp[tid] - v;
    __syncthreads();
    if (tid == 255) carryS += tmp[255];
    __syncthreads();
  }
  if (tid == 0) tot[b] = carryS;
}

__global__ __launch_bounds__(256) void k_baseF(const int* __restrict__ tot, int NSB,
                                               int N, int E, int* __restrict__ base2,
                                               int* __restrict__ off) {
  __shared__ int tmp[256];
  int tid = threadIdx.x;
  int v = (tid < NSB) ? tot[tid] : 0;
  tmp[tid] = v;
  __syncthreads();
  for (int d = 1; d < 256; d <<= 1) {
    int t = (tid >= d) ? tmp[tid - d] : 0;
    __syncthreads();
    tmp[tid] += t;
    __syncthreads();
  }
  base2[tid] = tmp[tid] - v;
  if (tid == 0) {
    base2[NSB] = E;
    off[N] = E;
  }
}

__global__ __launch_bounds__(256) void k_placeF(const int* __restrict__ dst,
                                                const int* __restrict__ src, int E,
                                                const int* __restrict__ bcnt,
                                                const int* __restrict__ base2,
                                                int* __restrict__ ebuf2) {
  __shared__ int lb[256];
  int k = blockIdx.x;
  int tid = threadIdx.x;
  lb[tid] = base2[tid] + bcnt[k * 256 + tid];
  __syncthreads();
  int lo = k * BEDG4, hi = min(lo + BEDG4, E);
  for (int i = lo + tid; i < hi; i += 256) {
    int d = NTL(&dst[i]);
    int s = NTL(&src[i]);
    int pos = atomicAdd(&lb[d >> 9], 1);
    ebuf2[pos] = (int)(((unsigned)(d & 511) << 17) | (unsigned)s);
  }
}

__global__ __launch_bounds__(256) void k_csrF(const int* __restrict__ ebuf2,
                                              const int* __restrict__ base2,
                                              const int* __restrict__ tot, int N,
                                              int* __restrict__ off,
                                              int* __restrict__ col) {
  __shared__ int cnt[512];
  __shared__ int cur[512];
  __shared__ int tmp[256];
  __shared__ int stage[CAP];
  int sb = blockIdx.x;
  int tid = threadIdx.x;
  int node0 = sb << 9;
  if (node0 >= N) return;
  int nn = min(512, N - node0);
  int lo = base2[sb];
  int t2 = tot[sb];

  cnt[tid] = 0;
  cnt[tid + 256] = 0;
  __syncthreads();
  for (int i = lo + tid; i < lo + t2; i += 256)
    atomicAdd(&cnt[(((unsigned)ebuf2[i]) >> 17) & 511], 1);
  __syncthreads();

  int v0 = cnt[2 * tid], v1 = cnt[2 * tid + 1];
  int s = v0 + v1;
  tmp[tid] = s;
  __syncthreads();
  for (int d = 1; d < 256; d <<= 1) {
    int t = (tid >= d) ? tmp[tid - d] : 0;
    __syncthreads();
    tmp[tid] += t;
    __syncthreads();
  }
  int excl = tmp[tid] - s;
  cnt[2 * tid] = excl;
  cnt[2 * tid + 1] = excl + v0;
  cur[2 * tid] = excl;
  cur[2 * tid + 1] = excl + v0;
  __syncthreads();

  for (int i = tid; i < nn; i += 256) off[node0 + i] = lo + cnt[i];

  if (t2 <= CAP) {
    for (int i = lo + tid; i < lo + t2; i += 256) {
      unsigned pk = (unsigned)ebuf2[i];
      int pos = atomicAdd(&cur[(pk >> 17) & 511], 1);
      stage[pos] = (int)(pk & 0x1FFFFu);
    }
    __syncthreads();
    for (int i = tid; i < t2; i += 256) col[lo + i] = stage[i];
  } else {
    for (int i = lo + tid; i < lo + t2; i += 256) {
      unsigned pk = (unsigned)ebuf2[i];
      int pos = atomicAdd(&cur[(pk >> 17) & 511], 1);
      col[lo + pos] = (int)(pk & 0x1FFFFu);
    }
  }
}

// ---------------- casts / weight prep ----------------
__global__ void k_cast(const float4* __restrict__ x, uint4* __restrict__ xb,
                       uint2* __restrict__ xq, int n8) {
  int i = blockIdx.x * blockDim.x + threadIdx.x;
  if (i >= n8) return;
  float4 a = x[i * 2], b = x[i * 2 + 1];
  uint4 o;
  o.x = (unsigned)f2bf(a.x) | ((unsigned)f2bf(a.y) << 16);
  o.y = (unsigned)f2bf(a.z) | ((unsigned)f2bf(a.w) << 16);
  o.z = (unsigned)f2bf(b.x) | ((unsigned)f2bf(b.y) << 16);
  o.w = (unsigned)f2bf(b.z) | ((unsigned)f2bf(b.w) << 16);
  xb[i] = o;
  unsigned lo = __builtin_amdgcn_cvt_pk_fp8_f32(a.x, a.y, 0, false);
  lo = __builtin_amdgcn_cvt_pk_fp8_f32(a.z, a.w, lo, true);
  unsigned hi = __builtin_amdgcn_cvt_pk_fp8_f32(b.x, b.y, 0, false);
  hi = __builtin_amdgcn_cvt_pk_fp8_f32(b.z, b.w, hi, true);
  xq[i] = make_uint2(lo, hi);
}

// Wth layout: [half][COLS][128] bf16. half0=Wl^T, half1=Wr^T.
__global__ void k_prepw(const float* __restrict__ W1l, const float* __restrict__ W1r,
                        const float* __restrict__ W2l, const float* __restrict__ W2r,
                        const float* __restrict__ W3l, const float* __restrict__ W3r,
                        unsigned short* __restrict__ Wth1, unsigned short* __restrict__ Wth2,
                        unsigned short* __restrict__ Wth3) {
  int idx = blockIdx.x * blockDim.x + threadIdx.x;
  if (idx < 32768) {
    int h = idx >> 14, c = (idx >> 7) & 127, k = idx & 127;
    const float* W = h ? W1r : W1l;
    Wth1[idx] = f2bf(W[k * 128 + c]);
  } else if (idx < 65536) {
    int j = idx - 32768;
    int h = j >> 14, c = (j >> 7) & 127, k = j & 127;
    const float* W = h ? W2r : W2l;
    Wth2[j] = f2bf(W[k * 128 + c]);
  } else if (idx < 65536 + 16384) {
    int j = idx - 65536;
    int h = j >> 13, c = (j >> 7) & 63, k = j & 127;
    float v = 0.f;
    if (c < NCLASS) v = (h ? W3r : W3l)[k * NCLASS + c];
    Wth3[j] = f2bf(v);
  }
}

// ------- mean aggregation, width 128, fp8 rows: 16 lanes/row, uint2/lane -------
// Tail-split: unmasked full-16-edge loop + one masked tail iteration.
__global__ void k_aggq(const char* __restrict__ Xq, const int* __restrict__ off,
                       const int* __restrict__ col, int n, uint4* __restrict__ out) {
  int wid = (blockIdx.x * blockDim.x + threadIdx.x) >> 6;
  int lane = threadIdx.x & 63;
  if (wid >= n) return;
  int g = lane >> 4, q = lane & 15;
  unsigned qb = (unsigned)q << 3;  // 8 B per lane
  int s = off[wid], e = off[wid + 1];
  float acc[8];
#pragma unroll
  for (int t = 0; t < 8; ++t) acc[t] = 0.f;
  int cnt = e - s;
  int jend = s + (cnt & ~15);
  for (int j = s; j < jend; j += 16) {
    int c0 = NTL(&col[j + g]);
    int c1 = NTL(&col[j + g + 4]);
    int c2 = NTL(&col[j + g + 8]);
    int c3 = NTL(&col[j + g + 12]);
    uint2 u0 = *(const uint2*)(Xq + (((unsigned)c0 << 7) + qb));
    uint2 u1 = *(const uint2*)(Xq + (((unsigned)c1 << 7) + qb));
    uint2 u2 = *(const uint2*)(Xq + (((unsigned)c2 << 7) + qb));
    uint2 u3 = *(const uint2*)(Xq + (((unsigned)c3 << 7) + qb));
    ACCQ2U(u0);
    ACCQ2U(u1);
    ACCQ2U(u2);
    ACCQ2U(u3);
  }
  if (jend < e) {
    int e1 = e - 1;
    int i0 = jend + g, i1 = i0 + 4, i2 = i0 + 8, i3 = i0 + 12;
    int c0 = NTL(&col[min(i0, e1)]);
    int c1 = NTL(&col[min(i1, e1)]);
    int c2 = NTL(&col[min(i2, e1)]);
    int c3 = NTL(&col[min(i3, e1)]);
    float s0 = (i0 < e) ? 1.f : 0.f;
    float s1 = (i1 < e) ? 1.f : 0.f;
    float s2 = (i2 < e) ? 1.f : 0.f;
    float s3 = (i3 < e) ? 1.f : 0.f;
    uint2 u0 = *(const uint2*)(Xq + (((unsigned)c0 << 7) + qb));
    uint2 u1 = *(const uint2*)(Xq + (((unsigned)c1 << 7) + qb));
    uint2 u2 = *(const uint2*)(Xq + (((unsigned)c2 << 7) + qb));
    uint2 u3 = *(const uint2*)(Xq + (((unsigned)c3 << 7) + qb));
    ACCQ2(u0, s0);
    ACCQ2(u1, s1);
    ACCQ2(u2, s2);
    ACCQ2(u3, s3);
  }
#pragma unroll
  for (int t = 0; t < 8; ++t) {
    acc[t] += __shfl_xor(acc[t], 16);
    acc[t] += __shfl_xor(acc[t], 32);
  }
  float inv = 1.0f / fmaxf((float)cnt, 1.0f);
  if (lane < 16) {
    uint4 o;
    o.x = (unsigned)f2bf(acc[0] * inv) | ((unsigned)f2bf(acc[1] * inv) << 16);
    o.y = (unsigned)f2bf(acc[2] * inv) | ((unsigned)f2bf(acc[3] * inv) << 16);
    o.z = (unsigned)f2bf(acc[4] * inv) | ((unsigned)f2bf(acc[5] * inv) << 16);
    o.w = (unsigned)f2bf(acc[6] * inv) | ((unsigned)f2bf(acc[7] * inv) << 16);
    out[(size_t)wid * 16 + q] = o;
  }
}

// ---------------- MFMA GEMM ----------------
// EPI 0: relu -> outB bf16 [n][128] AND (fp8*)outF [n][128]
// EPI 1: relu -> outB bf16 [n][128] AND outF f32 [n][128]
// EPI 3: cols 0..63 -> (fp8*)outB [n][64] (Y3q); cols 64..127 -> (bf16*)outF [n][64] (R3)
template <int COLS, int HALVES, int EPI>
__global__ __launch_bounds__(256) void k_gemm_mfma(
    const unsigned short* __restrict__ Aagg, const unsigned short* __restrict__ Aroot,
    const unsigned short* __restrict__ Wth, const float* __restrict__ bias, int n,
    float* __restrict__ outF, unsigned short* __restrict__ outB) {
  constexpr int RF = 4;
  constexpr int CF = 4;
  __shared__ unsigned short aS[128 * 128];
  __shared__ unsigned short wS[COLS * 128];
  int tid = threadIdx.x;
  int w = tid >> 6, lane = tid & 63, l15 = lane & 15, kg = lane >> 4;
  int rowBase = blockIdx.x * 128;
  int r0 = (w >> 1) * 64;
  int c0 = (w & 1) * 64;

  f32x4 acc[RF][CF];
#pragma unroll
  for (int i = 0; i < RF; ++i)
#pragma unroll
    for (int j = 0; j < CF; ++j) acc[i][j] = (f32x4){0.f, 0.f, 0.f, 0.f};

#pragma unroll
  for (int half = 0; half < HALVES; ++half) {
    if (half) __syncthreads();
    {
      const unsigned short* As = half ? Aroot : Aagg;
#pragma unroll
      for (int it = 0; it < 8; ++it) {
        int row = it * 16 + (tid >> 4);
        int g = rowBase + row;
        g = (g < n) ? g : (n - 1);
        int cb = (tid & 15) << 4;
        int sb = cb ^ ((row & 7) << 4);
        const char* src = (const char*)(As + (size_t)g * 128) + sb;
        char* dst = (char*)aS + it * 4096 + (tid >> 6) * 1024;
        GLOAD_LDS16(src, dst);
      }
      const unsigned short* Ws = Wth + (size_t)half * COLS * 128;
#pragma unroll
      for (int it = 0; it < COLS / 16; ++it) {
        int c = it * 16 + (tid >> 4);
        int cb = (tid & 15) << 4;
        int sb = cb ^ ((c & 7) << 4);
        const char* src = (const char*)(Ws + (size_t)c * 128) + sb;
        char* dst = (char*)wS + it * 4096 + (tid >> 6) * 1024;
        GLOAD_LDS16(src, dst);
      }
      asm volatile("s_waitcnt vmcnt(0)" ::: "memory");
      __syncthreads();
    }
#pragma unroll
    for (int ks = 0; ks < 4; ++ks) {
      int kb = ks * 64 + kg * 16;
      bf16x8 av[RF], bv[CF];
#pragma unroll
      for (int i = 0; i < RF; ++i) {
        int row = r0 + i * 16 + l15;
        av[i] = *(const bf16x8*)((const char*)aS + row * 256 + (kb ^ ((row & 7) << 4)));
      }
#pragma unroll
      for (int j = 0; j < CF; ++j) {
        int c = c0 + j * 16 + l15;
        bv[j] = *(const bf16x8*)((const char*)wS + c * 256 + (kb ^ ((c & 7) << 4)));
      }
#pragma unroll
      for (int i = 0; i < RF; ++i)
#pragma unroll
        for (int j = 0; j < CF; ++j)
          acc[i][j] = __builtin_amdgcn_mfma_f32_16x16x32_bf16(av[i], bv[j], acc[i][j], 0, 0, 0);
    }
  }

  if (EPI == 3) {
    bool leftHalf = (c0 == 0);
    unsigned char* Y3q = (unsigned char*)outB;
    unsigned short* R3b = (unsigned short*)outF;
    float bcol[CF];
#pragma unroll
    for (int j = 0; j < CF; ++j) {
      int c = c0 + j * 16 + l15;
      bcol[j] = (!leftHalf && (c - 64) < NCLASS) ? bias[c - 64] : 0.f;
    }
#pragma unroll
    for (int i = 0; i < RF; ++i) {
#pragma unroll
      for (int r = 0; r < 4; ++r) {
        int row = rowBase + r0 + i * 16 + kg * 4 + r;
        if (row >= n) continue;
#pragma unroll
        for (int j = 0; j < CF; ++j) {
          int c = c0 + j * 16 + l15;
          if (leftHalf) {
            unsigned pk = __builtin_amdgcn_cvt_pk_fp8_f32(acc[i][j][r], acc[i][j][r], 0, false);
            Y3q[(size_t)row * 64 + c] = (unsigned char)(pk & 0xff);
          } else {
            R3b[(size_t)row * 64 + (c - 64)] = f2bf(acc[i][j][r] + bcol[j]);
          }
        }
      }
    }
  } else {
    float bcol[CF];
#pragma unroll
    for (int j = 0; j < CF; ++j) bcol[j] = bias[c0 + j * 16 + l15];
#pragma unroll
    for (int i = 0; i < RF; ++i) {
#pragma unroll
      for (int r = 0; r < 4; ++r) {
        int row = rowBase + r0 + i * 16 + kg * 4 + r;
        if (row >= n) continue;
#pragma unroll
        for (int j = 0; j < CF; ++j) {
          float v = fmaxf(acc[i][j][r] + bcol[j], 0.f);
          int c = c0 + j * 16 + l15;
          outB[(size_t)row * 128 + c] = f2bf(v);
          if (EPI == 1) outF[(size_t)row * 128 + c] = v;
          if (EPI == 0) {
            unsigned pk = __builtin_amdgcn_cvt_pk_fp8_f32(v, v, 0, false);
            ((unsigned char*)outF)[(size_t)row * 128 + c] = (unsigned char)(pk & 0xff);
          }
        }
      }
    }
  }
}

// ------- layer-3: width-64 fp8 mean agg + bf16 root + log_softmax, 8 lanes/row -------
// Tail-split: unmasked full-16-edge loop + one masked tail iteration.
__global__ void k_agg3ls(const char* __restrict__ Y3q, const char* __restrict__ R3,
                         const int* __restrict__ off, const int* __restrict__ col, int n,
                         float* __restrict__ out) {
  int wid = (blockIdx.x * blockDim.x + threadIdx.x) >> 6;
  int lane = threadIdx.x & 63;
  if (wid >= n) return;
  int g = lane >> 3, q = lane & 7;
  unsigned qb = (unsigned)q << 3;  // 8 fp8 bytes per lane within a 64-B row
  int s = off[wid], e = off[wid + 1];
  float acc[8];
#pragma unroll
  for (int t = 0; t < 8; ++t) acc[t] = 0.f;
  int cnt = e - s;
  int jend = s + (cnt & ~15);
  for (int j = s; j < jend; j += 16) {
    int c0 = NTL(&col[j + g]);
    int c1 = NTL(&col[j + g + 8]);
    uint2 u0 = *(const uint2*)(Y3q + (((unsigned)c0 << 6) + qb));
    uint2 u1 = *(const uint2*)(Y3q + (((unsigned)c1 << 6) + qb));
    ACCQ2U(u0);
    ACCQ2U(u1);
  }
  if (jend < e) {
    int e1 = e - 1;
    int i0 = jend + g, i1 = i0 + 8;
    int c0 = NTL(&col[min(i0, e1)]);
    int c1 = NTL(&col[min(i1, e1)]);
    float s0 = (i0 < e) ? 1.f : 0.f;
    float s1 = (i1 < e) ? 1.f : 0.f;
    uint2 u0 = *(const uint2*)(Y3q + (((unsigned)c0 << 6) + qb));
    uint2 u1 = *(const uint2*)(Y3q + (((unsigned)c1 << 6) + qb));
    ACCQ2(u0, s0);
    ACCQ2(u1, s1);
  }
#pragma unroll
  for (int t = 0; t < 8; ++t) {
    acc[t] += __shfl_xor(acc[t], 8);
    acc[t] += __shfl_xor(acc[t], 16);
    acc[t] += __shfl_xor(acc[t], 32);
  }
  float inv = 1.0f / fmaxf((float)cnt, 1.0f);
  uint4 ur = *(const uint4*)(R3 + (((unsigned)wid << 7) + ((unsigned)q << 4)));
  float v[8];
  v[0] = fmaf(acc[0], inv, bflo(ur.x));
  v[1] = fmaf(acc[1], inv, bfhi(ur.x));
  v[2] = fmaf(acc[2], inv, bflo(ur.y));
  v[3] = fmaf(acc[3], inv, bfhi(ur.y));
  v[4] = fmaf(acc[4], inv, bflo(ur.z));
  v[5] = fmaf(acc[5], inv, bfhi(ur.z));
  v[6] = fmaf(acc[6], inv, bflo(ur.w));
  v[7] = fmaf(acc[7], inv, bfhi(ur.w));
  bool valid = q < 5;  // cols q*8..q*8+7 < 40
  float m = -INFINITY;
  if (valid) {
#pragma unroll
    for (int t = 0; t < 8; ++t) m = fmaxf(m, v[t]);
  }
  m = fmaxf(m, __shfl_xor(m, 1));
  m = fmaxf(m, __shfl_xor(m, 2));
  m = fmaxf(m, __shfl_xor(m, 4));
  float sum = 0.f;
  if (valid) {
#pragma unroll
    for (int t = 0; t < 8; ++t) sum += __expf(v[t] - m);
  }
  sum += __shfl_xor(sum, 1);
  sum += __shfl_xor(sum, 2);
  sum += __shfl_xor(sum, 4);
  float ls = __logf(sum);
  if (lane < 5) {
    float4 o0 = make_float4(v[0] - m - ls, v[1] - m - ls, v[2] - m - ls, v[3] - m - ls);
    float4 o1 = make_float4(v[4] - m - ls, v[5] - m - ls, v[6] - m - ls, v[7] - m - ls);
    float* op = out + (size_t)wid * NCLASS + lane * 8;
    *(float4*)op = o0;
    *(float4*)(op + 4) = o1;
  }
}

extern "C" void kernel_launch(void* const* d_in, const int* in_sizes, int n_in,
                              void* d_out, int out_size, void* d_ws, size_t ws_size,
                              hipStream_t stream) {
  const float* x = (const float*)d_in[0];
  const int* ei = (const int*)d_in[1];
  const float* W1l = (const float*)d_in[2];
  const float* b1 = (const float*)d_in[3];
  const float* W1r = (const float*)d_in[4];
  const float* W2l = (const float*)d_in[5];
  const float* b2 = (const float*)d_in[6];
  const float* W2r = (const float*)d_in[7];
  const float* W3l = (const float*)d_in[8];
  const float* b3 = (const float*)d_in[9];
  const float* W3r = (const float*)d_in[10];

  int N = in_sizes[0] / 128;
  int E = in_sizes[1] / 2;
  const int* src = ei;
  const int* dst = ei + E;
  int NSB = (N + 511) >> 9;  // <= 256 for N <= 131072
  int nbB = (E + BEDG4 - 1) / BEDG4;

  char* wptr = (char*)d_ws;
  auto alloc = [&](size_t bytes) {
    void* p = (void*)wptr;
    wptr += (bytes + 255) & ~(size_t)255;
    return p;
  };
  int* off = (int*)alloc((size_t)(N + 1) * 4);
  int* col = (int*)alloc((size_t)E * 4);
  int* bcnt = (int*)alloc((size_t)nbB * 256 * 4);
  int* tot = (int*)alloc(256 * 4);
  int* base2 = (int*)alloc(257 * 4);
  unsigned short* Wth1 = (unsigned short*)alloc(32768 * 2);
  unsigned short* Wth2 = (unsigned short*)alloc(32768 * 2);
  unsigned short* Wth3 = (unsigned short*)alloc(16384 * 2);
  unsigned short* xb = (unsigned short*)alloc((size_t)N * 128 * 2);
  unsigned short* mb = (unsigned short*)alloc((size_t)N * 128 * 2);
  unsigned short* h1 = (unsigned short*)alloc((size_t)N * 128 * 2);
  unsigned short* h2 = (unsigned short*)alloc((size_t)N * 128 * 2);
  unsigned char* xq = (unsigned char*)alloc((size_t)N * 128);
  unsigned char* h1q = (unsigned char*)alloc((size_t)N * 128);

  float* outLS = (float*)d_out;                     // [N][40]
  float* emb = (float*)d_out + (size_t)N * NCLASS;  // [N][128]

  // Aliases (lifetimes disjoint on the stream):
  int* ebuf2 = (int*)h2;                    // E ints; dead before gemm2 writes h2
  unsigned char* Y3q = (unsigned char*)mb;  // fp8 [N][64]; mb dead after gemm2
  unsigned short* R3b = h1;                 // bf16 [N][64]; h1 dead after gemm2

  // CSR build: single-level counting sort by 512-node range, no global atomics
  k_bcountF<<<nbB, 256, 0, stream>>>(dst, E, bcnt);
  k_bscanF<<<NSB, 256, 0, stream>>>(bcnt, nbB, tot);
  k_baseF<<<1, 256, 0, stream>>>(tot, NSB, N, E, base2, off);
  k_placeF<<<nbB, 256, 0, stream>>>(dst, src, E, bcnt, base2, ebuf2);
  k_csrF<<<NSB, 256, 0, stream>>>(ebuf2, base2, tot, N, off, col);

  int n8 = N * 16;
  k_cast<<<(n8 + 255) / 256, 256, 0, stream>>>((const float4*)x, (uint4*)xb, (uint2*)xq,
                                               n8);
  k_prepw<<<(81920 + 255) / 256, 256, 0, stream>>>(W1l, W1r, W2l, W2r, W3l, W3r, Wth1,
                                                   Wth2, Wth3);

  int ab = (N * 64 + 255) / 256;
  int gb = (N + 127) / 128;

  // layer 1: fp8 gather of xq -> mb; gemm writes h1 bf16 + h1q fp8
  k_aggq<<<ab, 256, 0, stream>>>((const char*)xq, off, col, N, (uint4*)mb);
  k_gemm_mfma<128, 2, 0><<<gb, 256, 0, stream>>>(mb, xb, Wth1, b1, N, (float*)h1q, h1);
  // layer 2: fp8 gather of h1q -> mb; gemm writes emb f32 + h2 bf16
  k_aggq<<<ab, 256, 0, stream>>>((const char*)h1q, off, col, N, (uint4*)mb);
  k_gemm_mfma<128, 2, 1><<<gb, 256, 0, stream>>>(mb, h1, Wth2, b2, N, emb, h2);
  // layer 3: project first (Y3q = fp8(h2@W3l), R3 = bf16(h2@W3r + b3)), then
  // width-64 fp8 gather + fused root add + log_softmax
  k_gemm_mfma<128, 1, 3><<<gb, 256, 0, stream>>>(h2, nullptr, Wth3, b3, N, (float*)R3b,
                                                 (unsigned short*)Y3q);
  k_agg3ls<<<ab, 256, 0, stream>>>((const char*)Y3q, (const char*)R3b, off, col, N, outLS);
}

// Round 15
// 257.208 us; speedup vs baseline: 1.1800x; 1.0698x over previous
//
#include <hip/hip_runtime.h>
#include <math.h>

#define NCLASS 40
#define BEDG4 4096  // edges per chunk block in CSR build
#define CAP 24576   // LDS col-staging capacity per 512-node sub-bucket

typedef float f32x4 __attribute__((ext_vector_type(4)));
typedef float f32x2 __attribute__((ext_vector_type(2)));
typedef __bf16 bf16x8 __attribute__((ext_vector_type(8)));

typedef __attribute__((address_space(1))) const void gv_t;
typedef __attribute__((address_space(3))) void lv_t;
#define GLOAD_LDS16(g, l) __builtin_amdgcn_global_load_lds((gv_t*)(g), (lv_t*)(l), 16, 0, 0)
#define NTL(p) __builtin_nontemporal_load(p)

__device__ inline unsigned short f2bf(float f) {
  unsigned u = __float_as_uint(f);
  unsigned r = (u + 0x7fff + ((u >> 16) & 1)) >> 16;
  return (unsigned short)r;
}
__device__ inline float bflo(unsigned v) { return __uint_as_float(v << 16); }
__device__ inline float bfhi(unsigned v) { return __uint_as_float(v & 0xffff0000u); }

// decode 8 fp8 (one uint2), accumulate with scale
#define ACCQ2(u, sc)                                                  \
  do {                                                                \
    f32x2 p_;                                                         \
    p_ = __builtin_amdgcn_cvt_pk_f32_fp8(u.x, false);                 \
    acc[0] = fmaf(p_.x, sc, acc[0]); acc[1] = fmaf(p_.y, sc, acc[1]); \
    p_ = __builtin_amdgcn_cvt_pk_f32_fp8(u.x, true);                  \
    acc[2] = fmaf(p_.x, sc, acc[2]); acc[3] = fmaf(p_.y, sc, acc[3]); \
    p_ = __builtin_amdgcn_cvt_pk_f32_fp8(u.y, false);                 \
    acc[4] = fmaf(p_.x, sc, acc[4]); acc[5] = fmaf(p_.y, sc, acc[5]); \
    p_ = __builtin_amdgcn_cvt_pk_f32_fp8(u.y, true);                  \
    acc[6] = fmaf(p_.x, sc, acc[6]); acc[7] = fmaf(p_.y, sc, acc[7]); \
  } while (0)

// ============ CSR build: single-level counting sort by 512-node range =========
__global__ __launch_bounds__(256) void k_bcountF(const int* __restrict__ dst, int E,
                                                 int* __restrict__ bcnt) {
  __shared__ int lc[256];
  int k = blockIdx.x;
  int tid = threadIdx.x;
  lc[tid] = 0;
  __syncthreads();
  int lo = k * BEDG4, hi = min(lo + BEDG4, E);
  for (int i = lo + tid; i < hi; i += 256) atomicAdd(&lc[NTL(&dst[i]) >> 9], 1);
  __syncthreads();
  bcnt[k * 256 + tid] = lc[tid];
}

__global__ __launch_bounds__(256) void k_bscanF(int* __restrict__ bcnt, int nbB,
                                                int* __restrict__ tot) {
  __shared__ int tmp[256];
  __shared__ int carryS;
  int b = blockIdx.x;
  int tid = threadIdx.x;
  if (tid == 0) carryS = 0;
  __syncthreads();
  for (int c0 = 0; c0 < nbB; c0 += 256) {
    int idx = c0 + tid;
    int v = (idx < nbB) ? bcnt[idx * 256 + b] : 0;
    tmp[tid] = v;
    __syncthreads();
    for (int d = 1; d < 256; d <<= 1) {
      int t = (tid >= d) ? tmp[tid - d] : 0;
      __syncthreads();
      tmp[tid] += t;
      __syncthreads();
    }
    if (idx < nbB) bcnt[idx * 256 + b] = carryS + tmp[tid] - v;
    __syncthreads();
    if (tid == 255) carryS += tmp[255];
    __syncthreads();
  }
  if (tid == 0) tot[b] = carryS;
}

__global__ __launch_bounds__(256) void k_baseF(const int* __restrict__ tot, int NSB,
                                               int N, int E, int* __restrict__ base2,
                                               int* __restrict__ off) {
  __shared__ int tmp[256];
  int tid = threadIdx.x;
  int v = (tid < NSB) ? tot[tid] : 0;
  tmp[tid] = v;
  __syncthreads();
  for (int d = 1; d < 256; d <<= 1) {
    int t = (tid >= d) ? tmp[tid - d] : 0;
    __syncthreads();
    tmp[tid] += t;
    __syncthreads();
  }
  base2[tid] = tmp[tid] - v;
  if (tid == 0) {
    base2[NSB] = E;
    off[N] = E;
  }
}

__global__ __launch_bounds__(256) void k_placeF(const int* __restrict__ dst,
                                                const int* __restrict__ src, int E,
                                                const int* __restrict__ bcnt,
                                                const int* __restrict__ base2,
                                                int* __restrict__ ebuf2) {
  __shared__ int lb[256];
  int k = blockIdx.x;
  int tid = threadIdx.x;
  lb[tid] = base2[tid] + bcnt[k * 256 + tid];
  __syncthreads();
  int lo = k * BEDG4, hi = min(lo + BEDG4, E);
  for (int i = lo + tid; i < hi; i += 256) {
    int d = NTL(&dst[i]);
    int s = NTL(&src[i]);
    int pos = atomicAdd(&lb[d >> 9], 1);
    ebuf2[pos] = (int)(((unsigned)(d & 511) << 17) | (unsigned)s);
  }
}

__global__ __launch_bounds__(256) void k_csrF(const int* __restrict__ ebuf2,
                                              const int* __restrict__ base2,
                                              const int* __restrict__ tot, int N,
                                              int* __restrict__ off,
                                              int* __restrict__ col) {
  __shared__ int cnt[512];
  __shared__ int cur[512];
  __shared__ int tmp[256];
  __shared__ int stage[CAP];
  int sb = blockIdx.x;
  int tid = threadIdx.x;
  int node0 = sb << 9;
  if (node0 >= N) return;
  int nn = min(512, N - node0);
  int lo = base2[sb];
  int t2 = tot[sb];

  cnt[tid] = 0;
  cnt[tid + 256] = 0;
  __syncthreads();
  for (int i = lo + tid; i < lo + t2; i += 256)
    atomicAdd(&cnt[(((unsigned)ebuf2[i]) >> 17) & 511], 1);
  __syncthreads();

  int v0 = cnt[2 * tid], v1 = cnt[2 * tid + 1];
  int s = v0 + v1;
  tmp[tid] = s;
  __syncthreads();
  for (int d = 1; d < 256; d <<= 1) {
    int t = (tid >= d) ? tmp[tid - d] : 0;
    __syncthreads();
    tmp[tid] += t;
    __syncthreads();
  }
  int excl = tmp[tid] - s;
  cnt[2 * tid] = excl;
  cnt[2 * tid + 1] = excl + v0;
  cur[2 * tid] = excl;
  cur[2 * tid + 1] = excl + v0;
  __syncthreads();

  for (int i = tid; i < nn; i += 256) off[node0 + i] = lo + cnt[i];

  if (t2 <= CAP) {
    for (int i = lo + tid; i < lo + t2; i += 256) {
      unsigned pk = (unsigned)ebuf2[i];
      int pos = atomicAdd(&cur[(pk >> 17) & 511], 1);
      stage[pos] = (int)(pk & 0x1FFFFu);
    }
    __syncthreads();
    for (int i = tid; i < t2; i += 256) col[lo + i] = stage[i];
  } else {
    for (int i = lo + tid; i < lo + t2; i += 256) {
      unsigned pk = (unsigned)ebuf2[i];
      int pos = atomicAdd(&cur[(pk >> 17) & 511], 1);
      col[lo + pos] = (int)(pk & 0x1FFFFu);
    }
  }
}

// ---------------- casts / weight prep ----------------
__global__ void k_cast(const float4* __restrict__ x, uint4* __restrict__ xb,
                       uint2* __restrict__ xq, int n8) {
  int i = blockIdx.x * blockDim.x + threadIdx.x;
  if (i >= n8) return;
  float4 a = x[i * 2], b = x[i * 2 + 1];
  uint4 o;
  o.x = (unsigned)f2bf(a.x) | ((unsigned)f2bf(a.y) << 16);
  o.y = (unsigned)f2bf(a.z) | ((unsigned)f2bf(a.w) << 16);
  o.z = (unsigned)f2bf(b.x) | ((unsigned)f2bf(b.y) << 16);
  o.w = (unsigned)f2bf(b.z) | ((unsigned)f2bf(b.w) << 16);
  xb[i] = o;
  unsigned lo = __builtin_amdgcn_cvt_pk_fp8_f32(a.x, a.y, 0, false);
  lo = __builtin_amdgcn_cvt_pk_fp8_f32(a.z, a.w, lo, true);
  unsigned hi = __builtin_amdgcn_cvt_pk_fp8_f32(b.x, b.y, 0, false);
  hi = __builtin_amdgcn_cvt_pk_fp8_f32(b.z, b.w, hi, true);
  xq[i] = make_uint2(lo, hi);
}

// Wth layout: [half][COLS][128] bf16. half0=Wl^T, half1=Wr^T.
__global__ void k_prepw(const float* __restrict__ W1l, const float* __restrict__ W1r,
                        const float* __restrict__ W2l, const float* __restrict__ W2r,
                        const float* __restrict__ W3l, const float* __restrict__ W3r,
                        unsigned short* __restrict__ Wth1, unsigned short* __restrict__ Wth2,
                        unsigned short* __restrict__ Wth3) {
  int idx = blockIdx.x * blockDim.x + threadIdx.x;
  if (idx < 32768) {
    int h = idx >> 14, c = (idx >> 7) & 127, k = idx & 127;
    const float* W = h ? W1r : W1l;
    Wth1[idx] = f2bf(W[k * 128 + c]);
  } else if (idx < 65536) {
    int j = idx - 32768;
    int h = j >> 14, c = (j >> 7) & 127, k = j & 127;
    const float* W = h ? W2r : W2l;
    Wth2[j] = f2bf(W[k * 128 + c]);
  } else if (idx < 65536 + 16384) {
    int j = idx - 65536;
    int h = j >> 13, c = (j >> 7) & 63, k = j & 127;
    float v = 0.f;
    if (c < NCLASS) v = (h ? W3r : W3l)[k * NCLASS + c];
    Wth3[j] = f2bf(v);
  }
}

// ------- mean aggregation, width 128, fp8 rows: 2 nodes/wave -------
// Per 32-lane half: 16 lanes/row (uint2/lane), 2 edge-groups, 4 loads in
// flight (8 edges/iter per node); 8 acc; 1 shuffle round.
__global__ void k_aggq(const char* __restrict__ Xq, const int* __restrict__ off,
                       const int* __restrict__ col, int n, uint4* __restrict__ out) {
  int gw = (blockIdx.x * blockDim.x + threadIdx.x) >> 6;
  int lane = threadIdx.x & 63;
  int node = gw * 2 + (lane >> 5);
  if (gw * 2 >= n) return;
  int l32 = lane & 31;
  int g = l32 >> 4, q = l32 & 15;
  unsigned qb = (unsigned)q << 3;  // 8 B per lane
  int nd = min(node, n - 1);
  int s = off[nd];
  int e = (node < n) ? off[nd + 1] : s;
  float acc[8];
#pragma unroll
  for (int t = 0; t < 8; ++t) acc[t] = 0.f;
  int cnt = e - s;
  int e1 = e - 1;
  for (int j = s; j < e; j += 8) {
    int i0 = j + g, i1 = i0 + 2, i2 = i0 + 4, i3 = i0 + 6;
    int c0 = NTL(&col[min(i0, e1)]);
    int c1 = NTL(&col[min(i1, e1)]);
    int c2 = NTL(&col[min(i2, e1)]);
    int c3 = NTL(&col[min(i3, e1)]);
    float s0 = (i0 < e) ? 1.f : 0.f;
    float s1 = (i1 < e) ? 1.f : 0.f;
    float s2 = (i2 < e) ? 1.f : 0.f;
    float s3 = (i3 < e) ? 1.f : 0.f;
    uint2 u0 = *(const uint2*)(Xq + (((unsigned)c0 << 7) + qb));
    uint2 u1 = *(const uint2*)(Xq + (((unsigned)c1 << 7) + qb));
    uint2 u2 = *(const uint2*)(Xq + (((unsigned)c2 << 7) + qb));
    uint2 u3 = *(const uint2*)(Xq + (((unsigned)c3 << 7) + qb));
    ACCQ2(u0, s0);
    ACCQ2(u1, s1);
    ACCQ2(u2, s2);
    ACCQ2(u3, s3);
  }
#pragma unroll
  for (int t = 0; t < 8; ++t) acc[t] += __shfl_xor(acc[t], 16);
  float inv = 1.0f / fmaxf((float)cnt, 1.0f);
  if (l32 < 16 && node < n) {
    uint4 o;
    o.x = (unsigned)f2bf(acc[0] * inv) | ((unsigned)f2bf(acc[1] * inv) << 16);
    o.y = (unsigned)f2bf(acc[2] * inv) | ((unsigned)f2bf(acc[3] * inv) << 16);
    o.z = (unsigned)f2bf(acc[4] * inv) | ((unsigned)f2bf(acc[5] * inv) << 16);
    o.w = (unsigned)f2bf(acc[6] * inv) | ((unsigned)f2bf(acc[7] * inv) << 16);
    out[(size_t)node * 16 + q] = o;
  }
}

// ---------------- MFMA GEMM ----------------
// EPI 0: relu -> outB bf16 [n][128] AND (fp8*)outF [n][128]
// EPI 1: relu -> outB bf16 [n][128] AND outF f32 [n][128]
// EPI 3: cols 0..63 -> (fp8*)outB [n][64] (Y3q); cols 64..127 -> (bf16*)outF [n][64] (R3)
template <int COLS, int HALVES, int EPI>
__global__ __launch_bounds__(256) void k_gemm_mfma(
    const unsigned short* __restrict__ Aagg, const unsigned short* __restrict__ Aroot,
    const unsigned short* __restrict__ Wth, const float* __restrict__ bias, int n,
    float* __restrict__ outF, unsigned short* __restrict__ outB) {
  constexpr int RF = 4;
  constexpr int CF = 4;
  __shared__ unsigned short aS[128 * 128];
  __shared__ unsigned short wS[COLS * 128];
  int tid = threadIdx.x;
  int w = tid >> 6, lane = tid & 63, l15 = lane & 15, kg = lane >> 4;
  int rowBase = blockIdx.x * 128;
  int r0 = (w >> 1) * 64;
  int c0 = (w & 1) * 64;

  f32x4 acc[RF][CF];
#pragma unroll
  for (int i = 0; i < RF; ++i)
#pragma unroll
    for (int j = 0; j < CF; ++j) acc[i][j] = (f32x4){0.f, 0.f, 0.f, 0.f};

#pragma unroll
  for (int half = 0; half < HALVES; ++half) {
    if (half) __syncthreads();
    {
      const unsigned short* As = half ? Aroot : Aagg;
#pragma unroll
      for (int it = 0; it < 8; ++it) {
        int row = it * 16 + (tid >> 4);
        int g = rowBase + row;
        g = (g < n) ? g : (n - 1);
        int cb = (tid & 15) << 4;
        int sb = cb ^ ((row & 7) << 4);
        const char* src = (const char*)(As + (size_t)g * 128) + sb;
        char* dst = (char*)aS + it * 4096 + (tid >> 6) * 1024;
        GLOAD_LDS16(src, dst);
      }
      const unsigned short* Ws = Wth + (size_t)half * COLS * 128;
#pragma unroll
      for (int it = 0; it < COLS / 16; ++it) {
        int c = it * 16 + (tid >> 4);
        int cb = (tid & 15) << 4;
        int sb = cb ^ ((c & 7) << 4);
        const char* src = (const char*)(Ws + (size_t)c * 128) + sb;
        char* dst = (char*)wS + it * 4096 + (tid >> 6) * 1024;
        GLOAD_LDS16(src, dst);
      }
      asm volatile("s_waitcnt vmcnt(0)" ::: "memory");
      __syncthreads();
    }
#pragma unroll
    for (int ks = 0; ks < 4; ++ks) {
      int kb = ks * 64 + kg * 16;
      bf16x8 av[RF], bv[CF];
#pragma unroll
      for (int i = 0; i < RF; ++i) {
        int row = r0 + i * 16 + l15;
        av[i] = *(const bf16x8*)((const char*)aS + row * 256 + (kb ^ ((row & 7) << 4)));
      }
#pragma unroll
      for (int j = 0; j < CF; ++j) {
        int c = c0 + j * 16 + l15;
        bv[j] = *(const bf16x8*)((const char*)wS + c * 256 + (kb ^ ((c & 7) << 4)));
      }
#pragma unroll
      for (int i = 0; i < RF; ++i)
#pragma unroll
        for (int j = 0; j < CF; ++j)
          acc[i][j] = __builtin_amdgcn_mfma_f32_16x16x32_bf16(av[i], bv[j], acc[i][j], 0, 0, 0);
    }
  }

  if (EPI == 3) {
    bool leftHalf = (c0 == 0);
    unsigned char* Y3q = (unsigned char*)outB;
    unsigned short* R3b = (unsigned short*)outF;
    float bcol[CF];
#pragma unroll
    for (int j = 0; j < CF; ++j) {
      int c = c0 + j * 16 + l15;
      bcol[j] = (!leftHalf && (c - 64) < NCLASS) ? bias[c - 64] : 0.f;
    }
#pragma unroll
    for (int i = 0; i < RF; ++i) {
#pragma unroll
      for (int r = 0; r < 4; ++r) {
        int row = rowBase + r0 + i * 16 + kg * 4 + r;
        if (row >= n) continue;
#pragma unroll
        for (int j = 0; j < CF; ++j) {
          int c = c0 + j * 16 + l15;
          if (leftHalf) {
            unsigned pk = __builtin_amdgcn_cvt_pk_fp8_f32(acc[i][j][r], acc[i][j][r], 0, false);
            Y3q[(size_t)row * 64 + c] = (unsigned char)(pk & 0xff);
          } else {
            R3b[(size_t)row * 64 + (c - 64)] = f2bf(acc[i][j][r] + bcol[j]);
          }
        }
      }
    }
  } else {
    float bcol[CF];
#pragma unroll
    for (int j = 0; j < CF; ++j) bcol[j] = bias[c0 + j * 16 + l15];
#pragma unroll
    for (int i = 0; i < RF; ++i) {
#pragma unroll
      for (int r = 0; r < 4; ++r) {
        int row = rowBase + r0 + i * 16 + kg * 4 + r;
        if (row >= n) continue;
#pragma unroll
        for (int j = 0; j < CF; ++j) {
          float v = fmaxf(acc[i][j][r] + bcol[j], 0.f);
          int c = c0 + j * 16 + l15;
          outB[(size_t)row * 128 + c] = f2bf(v);
          if (EPI == 1) outF[(size_t)row * 128 + c] = v;
          if (EPI == 0) {
            unsigned pk = __builtin_amdgcn_cvt_pk_fp8_f32(v, v, 0, false);
            ((unsigned char*)outF)[(size_t)row * 128 + c] = (unsigned char)(pk & 0xff);
          }
        }
      }
    }
  }
}

// ------- layer-3: width-64 fp8 mean agg + bf16 root + log_softmax, 2 nodes/wave -------
// Per 32-lane half: 8 lanes/row (uint2/lane), 4 edge-groups, 2 loads in flight
// (8 edges/iter per node); 8 acc; 2 reduce rounds; native exp/log softmax.
__global__ void k_agg3ls(const char* __restrict__ Y3q, const char* __restrict__ R3,
                         const int* __restrict__ off, const int* __restrict__ col, int n,
                         float* __restrict__ out) {
  int gw = (blockIdx.x * blockDim.x + threadIdx.x) >> 6;
  int lane = threadIdx.x & 63;
  if (gw * 2 >= n) return;
  int node = gw * 2 + (lane >> 5);
  int l32 = lane & 31;
  int g = l32 >> 3, q = l32 & 7;
  unsigned qb = (unsigned)q << 3;  // 8 fp8 bytes per lane within a 64-B row
  int nd = min(node, n - 1);
  int s = off[nd];
  int e = (node < n) ? off[nd + 1] : s;
  float acc[8];
#pragma unroll
  for (int t = 0; t < 8; ++t) acc[t] = 0.f;
  int cnt = e - s;
  int e1 = e - 1;
  for (int j = s; j < e; j += 8) {
    int i0 = j + g, i1 = i0 + 4;
    int c0 = NTL(&col[min(i0, e1)]);
    int c1 = NTL(&col[min(i1, e1)]);
    float s0 = (i0 < e) ? 1.f : 0.f;
    float s1 = (i1 < e) ? 1.f : 0.f;
    uint2 u0 = *(const uint2*)(Y3q + (((unsigned)c0 << 6) + qb));
    uint2 u1 = *(const uint2*)(Y3q + (((unsigned)c1 << 6) + qb));
    ACCQ2(u0, s0);
    ACCQ2(u1, s1);
  }
#pragma unroll
  for (int t = 0; t < 8; ++t) {
    acc[t] += __shfl_xor(acc[t], 8);
    acc[t] += __shfl_xor(acc[t], 16);
  }
  float inv = 1.0f / fmaxf((float)cnt, 1.0f);
  uint4 ur = *(const uint4*)(R3 + (((unsigned)nd << 7) + ((unsigned)q << 4)));
  float v[8];
  v[0] = fmaf(acc[0], inv, bflo(ur.x));
  v[1] = fmaf(acc[1], inv, bfhi(ur.x));
  v[2] = fmaf(acc[2], inv, bflo(ur.y));
  v[3] = fmaf(acc[3], inv, bfhi(ur.y));
  v[4] = fmaf(acc[4], inv, bflo(ur.z));
  v[5] = fmaf(acc[5], inv, bfhi(ur.z));
  v[6] = fmaf(acc[6], inv, bflo(ur.w));
  v[7] = fmaf(acc[7], inv, bfhi(ur.w));
  bool valid = q < 5;  // cols q*8..q*8+7 < 40
  float m = -INFINITY;
  if (valid) {
#pragma unroll
    for (int t = 0; t < 8; ++t) m = fmaxf(m, v[t]);
  }
  m = fmaxf(m, __shfl_xor(m, 1));
  m = fmaxf(m, __shfl_xor(m, 2));
  m = fmaxf(m, __shfl_xor(m, 4));
  float sum = 0.f;
  if (valid) {
#pragma unroll
    for (int t = 0; t < 8; ++t) sum += __expf(v[t] - m);
  }
  sum += __shfl_xor(sum, 1);
  sum += __shfl_xor(sum, 2);
  sum += __shfl_xor(sum, 4);
  float ls = __logf(sum);
  if (l32 < 5 && node < n) {
    float4 o0 = make_float4(v[0] - m - ls, v[1] - m - ls, v[2] - m - ls, v[3] - m - ls);
    float4 o1 = make_float4(v[4] - m - ls, v[5] - m - ls, v[6] - m - ls, v[7] - m - ls);
    float* op = out + (size_t)node * NCLASS + q * 8;
    *(float4*)op = o0;
    *(float4*)(op + 4) = o1;
  }
}

extern "C" void kernel_launch(void* const* d_in, const int* in_sizes, int n_in,
                              void* d_out, int out_size, void* d_ws, size_t ws_size,
                              hipStream_t stream) {
  const float* x = (const float*)d_in[0];
  const int* ei = (const int*)d_in[1];
  const float* W1l = (const float*)d_in[2];
  const float* b1 = (const float*)d_in[3];
  const float* W1r = (const float*)d_in[4];
  const float* W2l = (const float*)d_in[5];
  const float* b2 = (const float*)d_in[6];
  const float* W2r = (const float*)d_in[7];
  const float* W3l = (const float*)d_in[8];
  const float* b3 = (const float*)d_in[9];
  const float* W3r = (const float*)d_in[10];

  int N = in_sizes[0] / 128;
  int E = in_sizes[1] / 2;
  const int* src = ei;
  const int* dst = ei + E;
  int NSB = (N + 511) >> 9;  // <= 256 for N <= 131072
  int nbB = (E + BEDG4 - 1) / BEDG4;

  char* wptr = (char*)d_ws;
  auto alloc = [&](size_t bytes) {
    void* p = (void*)wptr;
    wptr += (bytes + 255) & ~(size_t)255;
    return p;
  };
  int* off = (int*)alloc((size_t)(N + 1) * 4);
  int* col = (int*)alloc((size_t)E * 4);
  int* bcnt = (int*)alloc((size_t)nbB * 256 * 4);
  int* tot = (int*)alloc(256 * 4);
  int* base2 = (int*)alloc(257 * 4);
  unsigned short* Wth1 = (unsigned short*)alloc(32768 * 2);
  unsigned short* Wth2 = (unsigned short*)alloc(32768 * 2);
  unsigned short* Wth3 = (unsigned short*)alloc(16384 * 2);
  unsigned short* xb = (unsigned short*)alloc((size_t)N * 128 * 2);
  unsigned short* mb = (unsigned short*)alloc((size_t)N * 128 * 2);
  unsigned short* h1 = (unsigned short*)alloc((size_t)N * 128 * 2);
  unsigned short* h2 = (unsigned short*)alloc((size_t)N * 128 * 2);
  unsigned char* xq = (unsigned char*)alloc((size_t)N * 128);
  unsigned char* h1q = (unsigned char*)alloc((size_t)N * 128);

  float* outLS = (float*)d_out;                     // [N][40]
  float* emb = (float*)d_out + (size_t)N * NCLASS;  // [N][128]

  // Aliases (lifetimes disjoint on the stream):
  int* ebuf2 = (int*)h2;                    // E ints; dead before gemm2 writes h2
  unsigned char* Y3q = (unsigned char*)mb;  // fp8 [N][64]; mb dead after gemm2
  unsigned short* R3b = h1;                 // bf16 [N][64]; h1 dead after gemm2

  // CSR build: single-level counting sort by 512-node range, no global atomics
  k_bcountF<<<nbB, 256, 0, stream>>>(dst, E, bcnt);
  k_bscanF<<<NSB, 256, 0, stream>>>(bcnt, nbB, tot);
  k_baseF<<<1, 256, 0, stream>>>(tot, NSB, N, E, base2, off);
  k_placeF<<<nbB, 256, 0, stream>>>(dst, src, E, bcnt, base2, ebuf2);
  k_csrF<<<NSB, 256, 0, stream>>>(ebuf2, base2, tot, N, off, col);

  int n8 = N * 16;
  k_cast<<<(n8 + 255) / 256, 256, 0, stream>>>((const float4*)x, (uint4*)xb, (uint2*)xq,
                                               n8);
  k_prepw<<<(81920 + 255) / 256, 256, 0, stream>>>(W1l, W1r, W2l, W2r, W3l, W3r, Wth1,
                                                   Wth2, Wth3);

  int nw2 = (N + 1) / 2;  // dual-node waves
  int ab2 = (nw2 * 64 + 255) / 256;
  int gb = (N + 127) / 128;

  // layer 1: fp8 gather of xq -> mb; gemm writes h1 bf16 + h1q fp8
  k_aggq<<<ab2, 256, 0, stream>>>((const char*)xq, off, col, N, (uint4*)mb);
  k_gemm_mfma<128, 2, 0><<<gb, 256, 0, stream>>>(mb, xb, Wth1, b1, N, (float*)h1q, h1);
  // layer 2: fp8 gather of h1q -> mb; gemm writes emb f32 + h2 bf16
  k_aggq<<<ab2, 256, 0, stream>>>((const char*)h1q, off, col, N, (uint4*)mb);
  k_gemm_mfma<128, 2, 1><<<gb, 256, 0, stream>>>(mb, h1, Wth2, b2, N, emb, h2);
  // layer 3: project first (Y3q = fp8(h2@W3l), R3 = bf16(h2@W3r + b3)), then
  // width-64 fp8 gather + fused root add + log_softmax
  k_gemm_mfma<128, 1, 3><<<gb, 256, 0, stream>>>(h2, nullptr, Wth3, b3, N, (float*)R3b,
                                                 (unsigned short*)Y3q);
  k_agg3ls<<<ab2, 256, 0, stream>>>((const char*)Y3q, (const char*)R3b, off, col, N, outLS);
}

// Round 16
// 251.563 us; speedup vs baseline: 1.2065x; 1.0224x over previous
//
#include <hip/hip_runtime.h>
#include <math.h>

#define NCLASS 40
#define BEDG4 4096  // edges per chunk block in CSR build
#define CAP 24576   // LDS col-staging capacity per 512-node sub-bucket

typedef float f32x4 __attribute__((ext_vector_type(4)));
typedef float f32x2 __attribute__((ext_vector_type(2)));
typedef __bf16 bf16x8 __attribute__((ext_vector_type(8)));

typedef __attribute__((address_space(1))) const void gv_t;
typedef __attribute__((address_space(3))) void lv_t;
#define GLOAD_LDS16(g, l) __builtin_amdgcn_global_load_lds((gv_t*)(g), (lv_t*)(l), 16, 0, 0)
#define NTL(p) __builtin_nontemporal_load(p)

__device__ inline unsigned short f2bf(float f) {
  unsigned u = __float_as_uint(f);
  unsigned r = (u + 0x7fff + ((u >> 16) & 1)) >> 16;
  return (unsigned short)r;
}
__device__ inline float bflo(unsigned v) { return __uint_as_float(v << 16); }
__device__ inline float bfhi(unsigned v) { return __uint_as_float(v & 0xffff0000u); }

// decode 8 fp8 (one uint2), accumulate with scale
#define ACCQ2(u, sc)                                                  \
  do {                                                                \
    f32x2 p_;                                                         \
    p_ = __builtin_amdgcn_cvt_pk_f32_fp8(u.x, false);                 \
    acc[0] = fmaf(p_.x, sc, acc[0]); acc[1] = fmaf(p_.y, sc, acc[1]); \
    p_ = __builtin_amdgcn_cvt_pk_f32_fp8(u.x, true);                  \
    acc[2] = fmaf(p_.x, sc, acc[2]); acc[3] = fmaf(p_.y, sc, acc[3]); \
    p_ = __builtin_amdgcn_cvt_pk_f32_fp8(u.y, false);                 \
    acc[4] = fmaf(p_.x, sc, acc[4]); acc[5] = fmaf(p_.y, sc, acc[5]); \
    p_ = __builtin_amdgcn_cvt_pk_f32_fp8(u.y, true);                  \
    acc[6] = fmaf(p_.x, sc, acc[6]); acc[7] = fmaf(p_.y, sc, acc[7]); \
  } while (0)

// ============ CSR build: single-level counting sort by 512-node range =========
__global__ __launch_bounds__(256) void k_bcountF(const int* __restrict__ dst, int E,
                                                 int* __restrict__ bcnt) {
  __shared__ int lc[256];
  int k = blockIdx.x;
  int tid = threadIdx.x;
  lc[tid] = 0;
  __syncthreads();
  int lo = k * BEDG4, hi = min(lo + BEDG4, E);
  for (int i = lo + tid; i < hi; i += 256) atomicAdd(&lc[NTL(&dst[i]) >> 9], 1);
  __syncthreads();
  bcnt[k * 256 + tid] = lc[tid];
}

__global__ __launch_bounds__(256) void k_bscanF(int* __restrict__ bcnt, int nbB,
                                                int* __restrict__ tot) {
  __shared__ int tmp[256];
  __shared__ int carryS;
  int b = blockIdx.x;
  int tid = threadIdx.x;
  if (tid == 0) carryS = 0;
  __syncthreads();
  for (int c0 = 0; c0 < nbB; c0 += 256) {
    int idx = c0 + tid;
    int v = (idx < nbB) ? bcnt[idx * 256 + b] : 0;
    tmp[tid] = v;
    __syncthreads();
    for (int d = 1; d < 256; d <<= 1) {
      int t = (tid >= d) ? tmp[tid - d] : 0;
      __syncthreads();
      tmp[tid] += t;
      __syncthreads();
    }
    if (idx < nbB) bcnt[idx * 256 + b] = carryS + tmp[tid] - v;
    __syncthreads();
    if (tid == 255) carryS += tmp[255];
    __syncthreads();
  }
  if (tid == 0) tot[b] = carryS;
}

__global__ __launch_bounds__(256) void k_baseF(const int* __restrict__ tot, int NSB,
                                               int N, int E, int* __restrict__ base2,
                                               int* __restrict__ off) {
  __shared__ int tmp[256];
  int tid = threadIdx.x;
  int v = (tid < NSB) ? tot[tid] : 0;
  tmp[tid] = v;
  __syncthreads();
  for (int d = 1; d < 256; d <<= 1) {
    int t = (tid >= d) ? tmp[tid - d] : 0;
    __syncthreads();
    tmp[tid] += t;
    __syncthreads();
  }
  base2[tid] = tmp[tid] - v;
  if (tid == 0) {
    base2[NSB] = E;
    off[N] = E;
  }
}

__global__ __launch_bounds__(256) void k_placeF(const int* __restrict__ dst,
                                                const int* __restrict__ src, int E,
                                                const int* __restrict__ bcnt,
                                                const int* __restrict__ base2,
                                                int* __restrict__ ebuf2) {
  __shared__ int lb[256];
  int k = blockIdx.x;
  int tid = threadIdx.x;
  lb[tid] = base2[tid] + bcnt[k * 256 + tid];
  __syncthreads();
  int lo = k * BEDG4, hi = min(lo + BEDG4, E);
  for (int i = lo + tid; i < hi; i += 256) {
    int d = NTL(&dst[i]);
    int s = NTL(&src[i]);
    int pos = atomicAdd(&lb[d >> 9], 1);
    ebuf2[pos] = (int)(((unsigned)(d & 511) << 17) | (unsigned)s);
  }
}

__global__ __launch_bounds__(256) void k_csrF(const int* __restrict__ ebuf2,
                                              const int* __restrict__ base2,
                                              const int* __restrict__ tot, int N,
                                              int* __restrict__ off,
                                              int* __restrict__ col) {
  __shared__ int cnt[512];
  __shared__ int cur[512];
  __shared__ int tmp[256];
  __shared__ int stage[CAP];
  int sb = blockIdx.x;
  int tid = threadIdx.x;
  int node0 = sb << 9;
  if (node0 >= N) return;
  int nn = min(512, N - node0);
  int lo = base2[sb];
  int t2 = tot[sb];

  cnt[tid] = 0;
  cnt[tid + 256] = 0;
  __syncthreads();
  for (int i = lo + tid; i < lo + t2; i += 256)
    atomicAdd(&cnt[(((unsigned)ebuf2[i]) >> 17) & 511], 1);
  __syncthreads();

  int v0 = cnt[2 * tid], v1 = cnt[2 * tid + 1];
  int s = v0 + v1;
  tmp[tid] = s;
  __syncthreads();
  for (int d = 1; d < 256; d <<= 1) {
    int t = (tid >= d) ? tmp[tid - d] : 0;
    __syncthreads();
    tmp[tid] += t;
    __syncthreads();
  }
  int excl = tmp[tid] - s;
  cnt[2 * tid] = excl;
  cnt[2 * tid + 1] = excl + v0;
  cur[2 * tid] = excl;
  cur[2 * tid + 1] = excl + v0;
  __syncthreads();

  for (int i = tid; i < nn; i += 256) off[node0 + i] = lo + cnt[i];

  if (t2 <= CAP) {
    for (int i = lo + tid; i < lo + t2; i += 256) {
      unsigned pk = (unsigned)ebuf2[i];
      int pos = atomicAdd(&cur[(pk >> 17) & 511], 1);
      stage[pos] = (int)(pk & 0x1FFFFu);
    }
    __syncthreads();
    for (int i = tid; i < t2; i += 256) col[lo + i] = stage[i];
  } else {
    for (int i = lo + tid; i < lo + t2; i += 256) {
      unsigned pk = (unsigned)ebuf2[i];
      int pos = atomicAdd(&cur[(pk >> 17) & 511], 1);
      col[lo + pos] = (int)(pk & 0x1FFFFu);
    }
  }
}

// ---------------- casts / weight prep ----------------
__global__ void k_cast(const float4* __restrict__ x, uint4* __restrict__ xb,
                       uint2* __restrict__ xq, int n8) {
  int i = blockIdx.x * blockDim.x + threadIdx.x;
  if (i >= n8) return;
  float4 a = x[i * 2], b = x[i * 2 + 1];
  uint4 o;
  o.x = (unsigned)f2bf(a.x) | ((unsigned)f2bf(a.y) << 16);
  o.y = (unsigned)f2bf(a.z) | ((unsigned)f2bf(a.w) << 16);
  o.z = (unsigned)f2bf(b.x) | ((unsigned)f2bf(b.y) << 16);
  o.w = (unsigned)f2bf(b.z) | ((unsigned)f2bf(b.w) << 16);
  xb[i] = o;
  unsigned lo = __builtin_amdgcn_cvt_pk_fp8_f32(a.x, a.y, 0, false);
  lo = __builtin_amdgcn_cvt_pk_fp8_f32(a.z, a.w, lo, true);
  unsigned hi = __builtin_amdgcn_cvt_pk_fp8_f32(b.x, b.y, 0, false);
  hi = __builtin_amdgcn_cvt_pk_fp8_f32(b.z, b.w, hi, true);
  xq[i] = make_uint2(lo, hi);
}

// Wth layout: [half][COLS][128] bf16. half0=Wl^T, half1=Wr^T.
__global__ void k_prepw(const float* __restrict__ W1l, const float* __restrict__ W1r,
                        const float* __restrict__ W2l, const float* __restrict__ W2r,
                        const float* __restrict__ W3l, const float* __restrict__ W3r,
                        unsigned short* __restrict__ Wth1, unsigned short* __restrict__ Wth2,
                        unsigned short* __restrict__ Wth3) {
  int idx = blockIdx.x * blockDim.x + threadIdx.x;
  if (idx < 32768) {
    int h = idx >> 14, c = (idx >> 7) & 127, k = idx & 127;
    const float* W = h ? W1r : W1l;
    Wth1[idx] = f2bf(W[k * 128 + c]);
  } else if (idx < 65536) {
    int j = idx - 32768;
    int h = j >> 14, c = (j >> 7) & 127, k = j & 127;
    const float* W = h ? W2r : W2l;
    Wth2[j] = f2bf(W[k * 128 + c]);
  } else if (idx < 65536 + 16384) {
    int j = idx - 65536;
    int h = j >> 13, c = (j >> 7) & 63, k = j & 127;
    float v = 0.f;
    if (c < NCLASS) v = (h ? W3r : W3l)[k * NCLASS + c];
    Wth3[j] = f2bf(v);
  }
}

// ------- mean aggregation, width 128, fp8 rows: 2 nodes/wave, 16 edges/iter -------
// Per 32-lane half: 16 lanes/row (uint2/lane), 2 edge-groups, 8 loads in
// flight (16 edges/iter per node); 8 acc; 1 shuffle round.
__global__ void k_aggq(const char* __restrict__ Xq, const int* __restrict__ off,
                       const int* __restrict__ col, int n, uint4* __restrict__ out) {
  int gw = (blockIdx.x * blockDim.x + threadIdx.x) >> 6;
  int lane = threadIdx.x & 63;
  int node = gw * 2 + (lane >> 5);
  if (gw * 2 >= n) return;
  int l32 = lane & 31;
  int g = l32 >> 4, q = l32 & 15;
  unsigned qb = (unsigned)q << 3;  // 8 B per lane
  int nd = min(node, n - 1);
  int s = off[nd];
  int e = (node < n) ? off[nd + 1] : s;
  float acc[8];
#pragma unroll
  for (int t = 0; t < 8; ++t) acc[t] = 0.f;
  int cnt = e - s;
  int e1 = e - 1;
  for (int j = s; j < e; j += 16) {
    int i0 = j + g, i1 = i0 + 2, i2 = i0 + 4, i3 = i0 + 6;
    int i4 = i0 + 8, i5 = i0 + 10, i6 = i0 + 12, i7 = i0 + 14;
    int c0 = NTL(&col[min(i0, e1)]);
    int c1 = NTL(&col[min(i1, e1)]);
    int c2 = NTL(&col[min(i2, e1)]);
    int c3 = NTL(&col[min(i3, e1)]);
    int c4 = NTL(&col[min(i4, e1)]);
    int c5 = NTL(&col[min(i5, e1)]);
    int c6 = NTL(&col[min(i6, e1)]);
    int c7 = NTL(&col[min(i7, e1)]);
    float s0 = (i0 < e) ? 1.f : 0.f;
    float s1 = (i1 < e) ? 1.f : 0.f;
    float s2 = (i2 < e) ? 1.f : 0.f;
    float s3 = (i3 < e) ? 1.f : 0.f;
    float s4 = (i4 < e) ? 1.f : 0.f;
    float s5 = (i5 < e) ? 1.f : 0.f;
    float s6 = (i6 < e) ? 1.f : 0.f;
    float s7 = (i7 < e) ? 1.f : 0.f;
    uint2 u0 = *(const uint2*)(Xq + (((unsigned)c0 << 7) + qb));
    uint2 u1 = *(const uint2*)(Xq + (((unsigned)c1 << 7) + qb));
    uint2 u2 = *(const uint2*)(Xq + (((unsigned)c2 << 7) + qb));
    uint2 u3 = *(const uint2*)(Xq + (((unsigned)c3 << 7) + qb));
    uint2 u4 = *(const uint2*)(Xq + (((unsigned)c4 << 7) + qb));
    uint2 u5 = *(const uint2*)(Xq + (((unsigned)c5 << 7) + qb));
    uint2 u6 = *(const uint2*)(Xq + (((unsigned)c6 << 7) + qb));
    uint2 u7 = *(const uint2*)(Xq + (((unsigned)c7 << 7) + qb));
    ACCQ2(u0, s0);
    ACCQ2(u1, s1);
    ACCQ2(u2, s2);
    ACCQ2(u3, s3);
    ACCQ2(u4, s4);
    ACCQ2(u5, s5);
    ACCQ2(u6, s6);
    ACCQ2(u7, s7);
  }
#pragma unroll
  for (int t = 0; t < 8; ++t) acc[t] += __shfl_xor(acc[t], 16);
  float inv = 1.0f / fmaxf((float)cnt, 1.0f);
  if (l32 < 16 && node < n) {
    uint4 o;
    o.x = (unsigned)f2bf(acc[0] * inv) | ((unsigned)f2bf(acc[1] * inv) << 16);
    o.y = (unsigned)f2bf(acc[2] * inv) | ((unsigned)f2bf(acc[3] * inv) << 16);
    o.z = (unsigned)f2bf(acc[4] * inv) | ((unsigned)f2bf(acc[5] * inv) << 16);
    o.w = (unsigned)f2bf(acc[6] * inv) | ((unsigned)f2bf(acc[7] * inv) << 16);
    out[(size_t)node * 16 + q] = o;
  }
}

// ---------------- MFMA GEMM ----------------
// EPI 0: relu -> outB bf16 [n][128] AND (fp8*)outF [n][128]
// EPI 1: relu -> outB bf16 [n][128] AND outF f32 [n][128]
// EPI 3: cols 0..63 -> (fp8*)outB [n][64] (Y3q); cols 64..127 -> (bf16*)outF [n][64] (R3)
template <int COLS, int HALVES, int EPI>
__global__ __launch_bounds__(256) void k_gemm_mfma(
    const unsigned short* __restrict__ Aagg, const unsigned short* __restrict__ Aroot,
    const unsigned short* __restrict__ Wth, const float* __restrict__ bias, int n,
    float* __restrict__ outF, unsigned short* __restrict__ outB) {
  constexpr int RF = 4;
  constexpr int CF = 4;
  __shared__ unsigned short aS[128 * 128];
  __shared__ unsigned short wS[COLS * 128];
  int tid = threadIdx.x;
  int w = tid >> 6, lane = tid & 63, l15 = lane & 15, kg = lane >> 4;
  int rowBase = blockIdx.x * 128;
  int r0 = (w >> 1) * 64;
  int c0 = (w & 1) * 64;

  f32x4 acc[RF][CF];
#pragma unroll
  for (int i = 0; i < RF; ++i)
#pragma unroll
    for (int j = 0; j < CF; ++j) acc[i][j] = (f32x4){0.f, 0.f, 0.f, 0.f};

#pragma unroll
  for (int half = 0; half < HALVES; ++half) {
    if (half) __syncthreads();
    {
      const unsigned short* As = half ? Aroot : Aagg;
#pragma unroll
      for (int it = 0; it < 8; ++it) {
        int row = it * 16 + (tid >> 4);
        int g = rowBase + row;
        g = (g < n) ? g : (n - 1);
        int cb = (tid & 15) << 4;
        int sb = cb ^ ((row & 7) << 4);
        const char* src = (const char*)(As + (size_t)g * 128) + sb;
        char* dst = (char*)aS + it * 4096 + (tid >> 6) * 1024;
        GLOAD_LDS16(src, dst);
      }
      const unsigned short* Ws = Wth + (size_t)half * COLS * 128;
#pragma unroll
      for (int it = 0; it < COLS / 16; ++it) {
        int c = it * 16 + (tid >> 4);
        int cb = (tid & 15) << 4;
        int sb = cb ^ ((c & 7) << 4);
        const char* src = (const char*)(Ws + (size_t)c * 128) + sb;
        char* dst = (char*)wS + it * 4096 + (tid >> 6) * 1024;
        GLOAD_LDS16(src, dst);
      }
      asm volatile("s_waitcnt vmcnt(0)" ::: "memory");
      __syncthreads();
    }
#pragma unroll
    for (int ks = 0; ks < 4; ++ks) {
      int kb = ks * 64 + kg * 16;
      bf16x8 av[RF], bv[CF];
#pragma unroll
      for (int i = 0; i < RF; ++i) {
        int row = r0 + i * 16 + l15;
        av[i] = *(const bf16x8*)((const char*)aS + row * 256 + (kb ^ ((row & 7) << 4)));
      }
#pragma unroll
      for (int j = 0; j < CF; ++j) {
        int c = c0 + j * 16 + l15;
        bv[j] = *(const bf16x8*)((const char*)wS + c * 256 + (kb ^ ((c & 7) << 4)));
      }
#pragma unroll
      for (int i = 0; i < RF; ++i)
#pragma unroll
        for (int j = 0; j < CF; ++j)
          acc[i][j] = __builtin_amdgcn_mfma_f32_16x16x32_bf16(av[i], bv[j], acc[i][j], 0, 0, 0);
    }
  }

  if (EPI == 3) {
    bool leftHalf = (c0 == 0);
    unsigned char* Y3q = (unsigned char*)outB;
    unsigned short* R3b = (unsigned short*)outF;
    float bcol[CF];
#pragma unroll
    for (int j = 0; j < CF; ++j) {
      int c = c0 + j * 16 + l15;
      bcol[j] = (!leftHalf && (c - 64) < NCLASS) ? bias[c - 64] : 0.f;
    }
#pragma unroll
    for (int i = 0; i < RF; ++i) {
#pragma unroll
      for (int r = 0; r < 4; ++r) {
        int row = rowBase + r0 + i * 16 + kg * 4 + r;
        if (row >= n) continue;
#pragma unroll
        for (int j = 0; j < CF; ++j) {
          int c = c0 + j * 16 + l15;
          if (leftHalf) {
            unsigned pk = __builtin_amdgcn_cvt_pk_fp8_f32(acc[i][j][r], acc[i][j][r], 0, false);
            Y3q[(size_t)row * 64 + c] = (unsigned char)(pk & 0xff);
          } else {
            R3b[(size_t)row * 64 + (c - 64)] = f2bf(acc[i][j][r] + bcol[j]);
          }
        }
      }
    }
  } else {
    float bcol[CF];
#pragma unroll
    for (int j = 0; j < CF; ++j) bcol[j] = bias[c0 + j * 16 + l15];
#pragma unroll
    for (int i = 0; i < RF; ++i) {
#pragma unroll
      for (int r = 0; r < 4; ++r) {
        int row = rowBase + r0 + i * 16 + kg * 4 + r;
        if (row >= n) continue;
#pragma unroll
        for (int j = 0; j < CF; ++j) {
          float v = fmaxf(acc[i][j][r] + bcol[j], 0.f);
          int c = c0 + j * 16 + l15;
          outB[(size_t)row * 128 + c] = f2bf(v);
          if (EPI == 1) outF[(size_t)row * 128 + c] = v;
          if (EPI == 0) {
            unsigned pk = __builtin_amdgcn_cvt_pk_fp8_f32(v, v, 0, false);
            ((unsigned char*)outF)[(size_t)row * 128 + c] = (unsigned char)(pk & 0xff);
          }
        }
      }
    }
  }
}

// ------- layer-3: width-64 fp8 mean agg + bf16 root + log_softmax, 2 nodes/wave -------
// Per 32-lane half: 8 lanes/row (uint2/lane), 4 edge-groups, 4 loads in flight
// (16 edges/iter per node); 8 acc; 2 reduce rounds; native exp/log softmax.
__global__ void k_agg3ls(const char* __restrict__ Y3q, const char* __restrict__ R3,
                         const int* __restrict__ off, const int* __restrict__ col, int n,
                         float* __restrict__ out) {
  int gw = (blockIdx.x * blockDim.x + threadIdx.x) >> 6;
  int lane = threadIdx.x & 63;
  if (gw * 2 >= n) return;
  int node = gw * 2 + (lane >> 5);
  int l32 = lane & 31;
  int g = l32 >> 3, q = l32 & 7;
  unsigned qb = (unsigned)q << 3;  // 8 fp8 bytes per lane within a 64-B row
  int nd = min(node, n - 1);
  int s = off[nd];
  int e = (node < n) ? off[nd + 1] : s;
  uint4 ur = *(const uint4*)(R3 + (((unsigned)nd << 7) + ((unsigned)q << 4)));  // hoisted
  float acc[8];
#pragma unroll
  for (int t = 0; t < 8; ++t) acc[t] = 0.f;
  int cnt = e - s;
  int e1 = e - 1;
  for (int j = s; j < e; j += 16) {
    int i0 = j + g, i1 = i0 + 4, i2 = i0 + 8, i3 = i0 + 12;
    int c0 = NTL(&col[min(i0, e1)]);
    int c1 = NTL(&col[min(i1, e1)]);
    int c2 = NTL(&col[min(i2, e1)]);
    int c3 = NTL(&col[min(i3, e1)]);
    float s0 = (i0 < e) ? 1.f : 0.f;
    float s1 = (i1 < e) ? 1.f : 0.f;
    float s2 = (i2 < e) ? 1.f : 0.f;
    float s3 = (i3 < e) ? 1.f : 0.f;
    uint2 u0 = *(const uint2*)(Y3q + (((unsigned)c0 << 6) + qb));
    uint2 u1 = *(const uint2*)(Y3q + (((unsigned)c1 << 6) + qb));
    uint2 u2 = *(const uint2*)(Y3q + (((unsigned)c2 << 6) + qb));
    uint2 u3 = *(const uint2*)(Y3q + (((unsigned)c3 << 6) + qb));
    ACCQ2(u0, s0);
    ACCQ2(u1, s1);
    ACCQ2(u2, s2);
    ACCQ2(u3, s3);
  }
#pragma unroll
  for (int t = 0; t < 8; ++t) {
    acc[t] += __shfl_xor(acc[t], 8);
    acc[t] += __shfl_xor(acc[t], 16);
  }
  float inv = 1.0f / fmaxf((float)cnt, 1.0f);
  float v[8];
  v[0] = fmaf(acc[0], inv, bflo(ur.x));
  v[1] = fmaf(acc[1], inv, bfhi(ur.x));
  v[2] = fmaf(acc[2], inv, bflo(ur.y));
  v[3] = fmaf(acc[3], inv, bfhi(ur.y));
  v[4] = fmaf(acc[4], inv, bflo(ur.z));
  v[5] = fmaf(acc[5], inv, bfhi(ur.z));
  v[6] = fmaf(acc[6], inv, bflo(ur.w));
  v[7] = fmaf(acc[7], inv, bfhi(ur.w));
  bool valid = q < 5;  // cols q*8..q*8+7 < 40
  float m = -INFINITY;
  if (valid) {
#pragma unroll
    for (int t = 0; t < 8; ++t) m = fmaxf(m, v[t]);
  }
  m = fmaxf(m, __shfl_xor(m, 1));
  m = fmaxf(m, __shfl_xor(m, 2));
  m = fmaxf(m, __shfl_xor(m, 4));
  float sum = 0.f;
  if (valid) {
#pragma unroll
    for (int t = 0; t < 8; ++t) sum += __expf(v[t] - m);
  }
  sum += __shfl_xor(sum, 1);
  sum += __shfl_xor(sum, 2);
  sum += __shfl_xor(sum, 4);
  float ls = __logf(sum);
  if (l32 < 5 && node < n) {
    float4 o0 = make_float4(v[0] - m - ls, v[1] - m - ls, v[2] - m - ls, v[3] - m - ls);
    float4 o1 = make_float4(v[4] - m - ls, v[5] - m - ls, v[6] - m - ls, v[7] - m - ls);
    float* op = out + (size_t)node * NCLASS + q * 8;
    *(float4*)op = o0;
    *(float4*)(op + 4) = o1;
  }
}

extern "C" void kernel_launch(void* const* d_in, const int* in_sizes, int n_in,
                              void* d_out, int out_size, void* d_ws, size_t ws_size,
                              hipStream_t stream) {
  const float* x = (const float*)d_in[0];
  const int* ei = (const int*)d_in[1];
  const float* W1l = (const float*)d_in[2];
  const float* b1 = (const float*)d_in[3];
  const float* W1r = (const float*)d_in[4];
  const float* W2l = (const float*)d_in[5];
  const float* b2 = (const float*)d_in[6];
  const float* W2r = (const float*)d_in[7];
  const float* W3l = (const float*)d_in[8];
  const float* b3 = (const float*)d_in[9];
  const float* W3r = (const float*)d_in[10];

  int N = in_sizes[0] / 128;
  int E = in_sizes[1] / 2;
  const int* src = ei;
  const int* dst = ei + E;
  int NSB = (N + 511) >> 9;  // <= 256 for N <= 131072
  int nbB = (E + BEDG4 - 1) / BEDG4;

  char* wptr = (char*)d_ws;
  auto alloc = [&](size_t bytes) {
    void* p = (void*)wptr;
    wptr += (bytes + 255) & ~(size_t)255;
    return p;
  };
  int* off = (int*)alloc((size_t)(N + 1) * 4);
  int* col = (int*)alloc((size_t)E * 4);
  int* bcnt = (int*)alloc((size_t)nbB * 256 * 4);
  int* tot = (int*)alloc(256 * 4);
  int* base2 = (int*)alloc(257 * 4);
  unsigned short* Wth1 = (unsigned short*)alloc(32768 * 2);
  unsigned short* Wth2 = (unsigned short*)alloc(32768 * 2);
  unsigned short* Wth3 = (unsigned short*)alloc(16384 * 2);
  unsigned short* xb = (unsigned short*)alloc((size_t)N * 128 * 2);
  unsigned short* mb = (unsigned short*)alloc((size_t)N * 128 * 2);
  unsigned short* h1 = (unsigned short*)alloc((size_t)N * 128 * 2);
  unsigned short* h2 = (unsigned short*)alloc((size_t)N * 128 * 2);
  unsigned char* xq = (unsigned char*)alloc((size_t)N * 128);
  unsigned char* h1q = (unsigned char*)alloc((size_t)N * 128);

  float* outLS = (float*)d_out;                     // [N][40]
  float* emb = (float*)d_out + (size_t)N * NCLASS;  // [N][128]

  // Aliases (lifetimes disjoint on the stream):
  int* ebuf2 = (int*)h2;                    // E ints; dead before gemm2 writes h2
  unsigned char* Y3q = (unsigned char*)mb;  // fp8 [N][64]; mb dead after gemm2
  unsigned short* R3b = h1;                 // bf16 [N][64]; h1 dead after gemm2

  // CSR build: single-level counting sort by 512-node range, no global atomics
  k_bcountF<<<nbB, 256, 0, stream>>>(dst, E, bcnt);
  k_bscanF<<<NSB, 256, 0, stream>>>(bcnt, nbB, tot);
  k_baseF<<<1, 256, 0, stream>>>(tot, NSB, N, E, base2, off);
  k_placeF<<<nbB, 256, 0, stream>>>(dst, src, E, bcnt, base2, ebuf2);
  k_csrF<<<NSB, 256, 0, stream>>>(ebuf2, base2, tot, N, off, col);

  int n8 = N * 16;
  k_cast<<<(n8 + 255) / 256, 256, 0, stream>>>((const float4*)x, (uint4*)xb, (uint2*)xq,
                                               n8);
  k_prepw<<<(81920 + 255) / 256, 256, 0, stream>>>(W1l, W1r, W2l, W2r, W3l, W3r, Wth1,
                                                   Wth2, Wth3);

  int nw2 = (N + 1) / 2;  // dual-node waves
  int ab2 = (nw2 * 64 + 255) / 256;
  int gb = (N + 127) / 128;

  // layer 1: fp8 gather of xq -> mb; gemm writes h1 bf16 + h1q fp8
  k_aggq<<<ab2, 256, 0, stream>>>((const char*)xq, off, col, N, (uint4*)mb);
  k_gemm_mfma<128, 2, 0><<<gb, 256, 0, stream>>>(mb, xb, Wth1, b1, N, (float*)h1q, h1);
  // layer 2: fp8 gather of h1q -> mb; gemm writes emb f32 + h2 bf16
  k_aggq<<<ab2, 256, 0, stream>>>((const char*)h1q, off, col, N, (uint4*)mb);
  k_gemm_mfma<128, 2, 1><<<gb, 256, 0, stream>>>(mb, h1, Wth2, b2, N, emb, h2);
  // layer 3: project first (Y3q = fp8(h2@W3l), R3 = bf16(h2@W3r + b3)), then
  // width-64 fp8 gather + fused root add + log_softmax
  k_gemm_mfma<128, 1, 3><<<gb, 256, 0, stream>>>(h2, nullptr, Wth3, b3, N, (float*)R3b,
                                                 (unsigned short*)Y3q);
  k_agg3ls<<<ab2, 256, 0, stream>>>((const char*)Y3q, (const char*)R3b, off, col, N, outLS);
}